// Round 1
// baseline (5504.831 us; speedup 1.0000x reference)
//
#include <hip/hip_runtime.h>
#include <math.h>

#define D_MODEL  1024
#define D_STATE  16
#define D_CONV   4
#define D_INNER  2048
#define DT_RANK  64
#define NUM_BLK  4
#define BATCH    2
#define SEQLEN   1024
#define ML       (BATCH*SEQLEN)   // 2048 rows (b*l flattened)
#define XPROJ_N  (DT_RANK + 2*D_STATE)  // 96

__device__ __forceinline__ float silu_f(float x) {
    return x / (1.0f + __expf(-x));
}

__device__ __forceinline__ float softplus_f(float x) {
    // log1p(exp(x)), stable
    if (x > 15.0f) return x;
    return __logf(1.0f + __expf(x));
}

// ---------------------------------------------------------------------------
// Embedding: h[b,l,d] = x[b,l]*emb_w[d] + emb_b[d]
// ---------------------------------------------------------------------------
__global__ __launch_bounds__(256) void embed_kernel(
    const float* __restrict__ x, const float* __restrict__ ew,
    const float* __restrict__ eb, float* __restrict__ h)
{
    int t  = blockIdx.x * 256 + threadIdx.x;   // 0 .. 2*1024*1024-1
    int d  = t & (D_MODEL - 1);
    int bl = t >> 10;
    h[t] = fmaf(x[bl], ew[d], eb[d]);
}

// ---------------------------------------------------------------------------
// Generic NT GEMM: C[m,n] = act( sum_k A[m,k]*W[n,k] + bias[n] )
// A: (M x K) row-major w/ stride lda; W: (N x K) row-major w/ stride ldw.
// 64x64 tile, BK=16, 256 threads, 4x4 per thread.
// ACT: 0 none, 1 softplus(+bias), 2 silu
// ---------------------------------------------------------------------------
template <int ACT>
__global__ __launch_bounds__(256) void gemm_nt(
    const float* __restrict__ A, int lda,
    const float* __restrict__ W, int ldw,
    const float* __restrict__ bias,
    float* __restrict__ C, int ldc,
    int M, int N, int K)
{
    const int BM = 64, BN = 64, BK = 16;
    __shared__ float As[BK][BM];
    __shared__ float Ws[BK][BN];

    int tid = threadIdx.x;
    int bx  = blockIdx.x;   // along N
    int by  = blockIdx.y;   // along M
    int tx  = tid & 15;     // 0..15  -> 4 cols each
    int ty  = tid >> 4;     // 0..15  -> 4 rows each

    // loader mapping: each thread loads one float4 along K
    int lr = tid >> 2;          // 0..63 tile row
    int lk = (tid & 3) * 4;     // 0,4,8,12

    int am = by * BM + lr;      // global A row (M is always multiple of 64 here)
    int wn = bx * BN + lr;      // global W row
    bool wok = (wn < N);

    const float* Ap = A + (size_t)am * lda + lk;
    const float* Wp = wok ? (W + (size_t)wn * ldw + lk) : W;

    float acc[4][4] = {};

    for (int kt = 0; kt < K; kt += BK) {
        float4 av = *(const float4*)(Ap + kt);
        float4 wv = wok ? *(const float4*)(Wp + kt) : make_float4(0.f,0.f,0.f,0.f);

        __syncthreads();
        As[lk+0][lr] = av.x; As[lk+1][lr] = av.y;
        As[lk+2][lr] = av.z; As[lk+3][lr] = av.w;
        Ws[lk+0][lr] = wv.x; Ws[lk+1][lr] = wv.y;
        Ws[lk+2][lr] = wv.z; Ws[lk+3][lr] = wv.w;
        __syncthreads();

        #pragma unroll
        for (int k = 0; k < BK; k++) {
            float4 a = *(const float4*)&As[k][ty*4];
            float4 b = *(const float4*)&Ws[k][tx*4];
            float ar[4] = {a.x, a.y, a.z, a.w};
            float br[4] = {b.x, b.y, b.z, b.w};
            #pragma unroll
            for (int i = 0; i < 4; i++)
                #pragma unroll
                for (int j = 0; j < 4; j++)
                    acc[i][j] = fmaf(ar[i], br[j], acc[i][j]);
        }
    }

    int m0 = by * BM + ty * 4;
    int n0 = bx * BN + tx * 4;
    #pragma unroll
    for (int i = 0; i < 4; i++) {
        #pragma unroll
        for (int j = 0; j < 4; j++) {
            int n = n0 + j;
            if (n < N) {
                float v = acc[i][j];
                if (ACT == 1) v = softplus_f(v + bias[n]);
                else if (ACT == 2) v = silu_f(v);
                C[(size_t)(m0 + i) * ldc + n] = v;
            }
        }
    }
}

// ---------------------------------------------------------------------------
// Causal depthwise conv (width 4) + silu.
// xx = xz[..., 0:D_INNER] (row stride 2*D_INNER)
// u[b,l,d] = silu( cb[d] + sum_k cw[d,k]*xx[b, l-3+k, d] )
// ---------------------------------------------------------------------------
__global__ __launch_bounds__(256) void conv_silu_kernel(
    const float* __restrict__ xz, const float* __restrict__ cw,
    const float* __restrict__ cb, float* __restrict__ u)
{
    int t  = blockIdx.x * 256 + threadIdx.x;  // 0 .. ML*D_INNER-1
    int d  = t & (D_INNER - 1);
    int bl = t >> 11;
    int l  = bl & (SEQLEN - 1);

    float4 w = *(const float4*)(cw + d * 4);
    float wk[4] = {w.x, w.y, w.z, w.w};
    float acc = cb[d];

    const float* xx = xz + (size_t)bl * (2 * D_INNER) + d;
    #pragma unroll
    for (int k = 0; k < 4; k++) {
        int ls = l + k - 3;
        if (ls >= 0)
            acc = fmaf(wk[k], xx[(ptrdiff_t)(k - 3) * (2 * D_INNER)], acc);
    }
    u[t] = silu_f(acc);
}

// ---------------------------------------------------------------------------
// Selective scan. One thread per (b,d), 16 states in registers.
// Reads dt,u (coalesced), B/C rows from x_dbl (wave-uniform -> broadcast),
// z from xz. Writes y IN PLACE over dt (same thread reads before writing).
// y[b,l,d] = (sum_n state*C + D[d]*u) * silu(z)
// ---------------------------------------------------------------------------
__global__ __launch_bounds__(256) void scan_kernel(
    const float* __restrict__ dt, const float* __restrict__ u,
    const float* __restrict__ xdbl, const float* __restrict__ xz,
    const float* __restrict__ A_log, const float* __restrict__ Dp,
    float* __restrict__ y)
{
    int t = blockIdx.x * 256 + threadIdx.x;   // 0..4095
    int b = t >> 11;
    int d = t & (D_INNER - 1);

    float Av[D_STATE];
    #pragma unroll
    for (int n = 0; n < D_STATE; n++)
        Av[n] = -__expf(A_log[d * D_STATE + n]);
    float Dd = Dp[d];

    float st[D_STATE] = {};

    const float* xr = xdbl + (size_t)b * SEQLEN * XPROJ_N;
    size_t idx  = (size_t)b * SEQLEN * D_INNER + d;
    size_t zidx = (size_t)b * SEQLEN * (2 * D_INNER) + D_INNER + d;

    for (int l = 0; l < SEQLEN; l++) {
        float dtv = dt[idx];
        float uv  = u[idx];
        float du  = dtv * uv;
        float yt  = 0.0f;
        #pragma unroll
        for (int n = 0; n < D_STATE; n++) {
            float Bn = xr[DT_RANK + n];
            float Cn = xr[DT_RANK + D_STATE + n];
            float s  = fmaf(st[n], __expf(dtv * Av[n]), du * Bn);
            st[n] = s;
            yt = fmaf(s, Cn, yt);
        }
        float zv = xz[zidx];
        y[idx] = (yt + Dd * uv) * silu_f(zv);

        idx  += D_INNER;
        zidx += 2 * D_INNER;
        xr   += XPROJ_N;
    }
}

// ---------------------------------------------------------------------------
extern "C" void kernel_launch(void* const* d_in, const int* in_sizes, int n_in,
                              void* d_out, int out_size, void* d_ws, size_t ws_size,
                              hipStream_t stream)
{
    const float* x     = (const float*)d_in[0];
    const float* emb_w = (const float*)d_in[1];
    const float* emb_b = (const float*)d_in[2];
    const float* inw   = (const float*)d_in[3];   // (4, 4096, 1024)
    const float* cw    = (const float*)d_in[4];   // (4, 2048, 4)
    const float* cb    = (const float*)d_in[5];   // (4, 2048)
    const float* xpw   = (const float*)d_in[6];   // (4, 96, 2048)
    const float* dtw   = (const float*)d_in[7];   // (4, 2048, 64)
    const float* dtb   = (const float*)d_in[8];   // (4, 2048)
    const float* Alog  = (const float*)d_in[9];   // (4, 2048, 16)
    const float* Dpar  = (const float*)d_in[10];  // (4, 2048)
    const float* outw  = (const float*)d_in[11];  // (4, 1024, 2048)

    float* out = (float*)d_out;

    // workspace layout (floats)
    float* ws  = (float*)d_ws;
    float* h   = ws;                    // 2*1024*1024      =  2,097,152
    float* xz  = h  + 2097152;          // 2*1024*4096      =  8,388,608
    float* u   = xz + 8388608;          // 2*1024*2048      =  4,194,304
    float* xd  = u  + 4194304;          // 2*1024*96        =    196,608
    float* dt  = xd + 196608;           // 2*1024*2048      =  4,194,304  (y in-place)

    embed_kernel<<<(ML * D_MODEL) / 256, 256, 0, stream>>>(x, emb_w, emb_b, h);

    for (int i = 0; i < NUM_BLK; i++) {
        const float* inw_i  = inw  + (size_t)i * (2 * D_INNER) * D_MODEL;
        const float* cw_i   = cw   + (size_t)i * D_INNER * D_CONV;
        const float* cb_i   = cb   + (size_t)i * D_INNER;
        const float* xpw_i  = xpw  + (size_t)i * XPROJ_N * D_INNER;
        const float* dtw_i  = dtw  + (size_t)i * D_INNER * DT_RANK;
        const float* dtb_i  = dtb  + (size_t)i * D_INNER;
        const float* Alog_i = Alog + (size_t)i * D_INNER * D_STATE;
        const float* Dp_i   = Dpar + (size_t)i * D_INNER;
        const float* outw_i = outw + (size_t)i * D_MODEL * D_INNER;

        // xz = h @ in_w^T   (M=2048, N=4096, K=1024)
        gemm_nt<0><<<dim3((2 * D_INNER) / 64, ML / 64), 256, 0, stream>>>(
            h, D_MODEL, inw_i, D_MODEL, nullptr, xz, 2 * D_INNER,
            ML, 2 * D_INNER, D_MODEL);

        // u = silu(conv(xx))
        conv_silu_kernel<<<(ML * D_INNER) / 256, 256, 0, stream>>>(xz, cw_i, cb_i, u);

        // x_dbl = u @ xp_w^T  (M=2048, N=96, K=2048)
        gemm_nt<0><<<dim3((XPROJ_N + 63) / 64, ML / 64), 256, 0, stream>>>(
            u, D_INNER, xpw_i, D_INNER, nullptr, xd, XPROJ_N,
            ML, XPROJ_N, D_INNER);

        // dt = softplus(dt_lo @ dt_w^T + dt_b)  (M=2048, N=2048, K=64)
        gemm_nt<1><<<dim3(D_INNER / 64, ML / 64), 256, 0, stream>>>(
            xd, XPROJ_N, dtw_i, DT_RANK, dtb_i, dt, D_INNER,
            ML, D_INNER, DT_RANK);

        // selective scan; y written in-place over dt
        scan_kernel<<<(BATCH * D_INNER) / 256, 256, 0, stream>>>(
            dt, u, xd, xz, Alog_i, Dp_i, dt);

        // h_next = silu(y @ out_w^T)  (M=2048, N=1024, K=2048)
        float* dst = (i == NUM_BLK - 1) ? out : h;
        gemm_nt<2><<<dim3(D_MODEL / 64, ML / 64), 256, 0, stream>>>(
            dt, D_INNER, outw_i, D_INNER, nullptr, dst, D_MODEL,
            ML, D_MODEL, D_INNER);
    }
}

// Round 2
// 2437.352 us; speedup vs baseline: 2.2585x; 2.2585x over previous
//
#include <hip/hip_runtime.h>
#include <math.h>

#define D_MODEL  1024
#define D_STATE  16
#define D_CONV   4
#define D_INNER  2048
#define DT_RANK  64
#define NUM_BLK  4
#define BATCH    2
#define SEQLEN   1024
#define ML       (BATCH*SEQLEN)   // 2048 rows (b*l flattened)
#define XPROJ_N  (DT_RANK + 2*D_STATE)  // 96
#define CH       32               // chunks per sequence
#define CL       32               // chunk length (CH*CL == SEQLEN)

__device__ __forceinline__ float silu_f(float x) {
    return x / (1.0f + __expf(-x));
}

__device__ __forceinline__ float softplus_f(float x) {
    if (x > 15.0f) return x;
    return __logf(1.0f + __expf(x));
}

// ---------------------------------------------------------------------------
// Embedding: h[b,l,d] = x[b,l]*emb_w[d] + emb_b[d]
// ---------------------------------------------------------------------------
__global__ __launch_bounds__(256) void embed_kernel(
    const float* __restrict__ x, const float* __restrict__ ew,
    const float* __restrict__ eb, float* __restrict__ h)
{
    int t  = blockIdx.x * 256 + threadIdx.x;
    int d  = t & (D_MODEL - 1);
    int bl = t >> 10;
    h[t] = fmaf(x[bl], ew[d], eb[d]);
}

// ---------------------------------------------------------------------------
// Generic NT GEMM: C[m,n] = act( sum_k A[m,k]*W[n,k] + bias[n] )
// 64x64 tile, BK=16, 256 threads, 4x4 per thread.
// ACT: 0 none, 1 softplus(+bias), 2 silu
// ---------------------------------------------------------------------------
template <int ACT>
__global__ __launch_bounds__(256) void gemm_nt(
    const float* __restrict__ A, int lda,
    const float* __restrict__ W, int ldw,
    const float* __restrict__ bias,
    float* __restrict__ C, int ldc,
    int M, int N, int K)
{
    const int BM = 64, BN = 64, BK = 16;
    __shared__ float As[BK][BM];
    __shared__ float Ws[BK][BN];

    int tid = threadIdx.x;
    int bx  = blockIdx.x;
    int by  = blockIdx.y;
    int tx  = tid & 15;
    int ty  = tid >> 4;

    int lr = tid >> 2;
    int lk = (tid & 3) * 4;

    int am = by * BM + lr;
    int wn = bx * BN + lr;
    bool wok = (wn < N);

    const float* Ap = A + (size_t)am * lda + lk;
    const float* Wp = wok ? (W + (size_t)wn * ldw + lk) : W;

    float acc[4][4] = {};

    for (int kt = 0; kt < K; kt += BK) {
        float4 av = *(const float4*)(Ap + kt);
        float4 wv = wok ? *(const float4*)(Wp + kt) : make_float4(0.f,0.f,0.f,0.f);

        __syncthreads();
        As[lk+0][lr] = av.x; As[lk+1][lr] = av.y;
        As[lk+2][lr] = av.z; As[lk+3][lr] = av.w;
        Ws[lk+0][lr] = wv.x; Ws[lk+1][lr] = wv.y;
        Ws[lk+2][lr] = wv.z; Ws[lk+3][lr] = wv.w;
        __syncthreads();

        #pragma unroll
        for (int k = 0; k < BK; k++) {
            float4 a = *(const float4*)&As[k][ty*4];
            float4 b = *(const float4*)&Ws[k][tx*4];
            float ar[4] = {a.x, a.y, a.z, a.w};
            float br[4] = {b.x, b.y, b.z, b.w};
            #pragma unroll
            for (int i = 0; i < 4; i++)
                #pragma unroll
                for (int j = 0; j < 4; j++)
                    acc[i][j] = fmaf(ar[i], br[j], acc[i][j]);
        }
    }

    int m0 = by * BM + ty * 4;
    int n0 = bx * BN + tx * 4;
    #pragma unroll
    for (int i = 0; i < 4; i++) {
        #pragma unroll
        for (int j = 0; j < 4; j++) {
            int n = n0 + j;
            if (n < N) {
                float v = acc[i][j];
                if (ACT == 1) v = softplus_f(v + bias[n]);
                else if (ACT == 2) v = silu_f(v);
                C[(size_t)(m0 + i) * ldc + n] = v;
            }
        }
    }
}

// ---------------------------------------------------------------------------
// Causal depthwise conv (width 4) + silu.
// ---------------------------------------------------------------------------
__global__ __launch_bounds__(256) void conv_silu_kernel(
    const float* __restrict__ xz, const float* __restrict__ cw,
    const float* __restrict__ cb, float* __restrict__ u)
{
    int t  = blockIdx.x * 256 + threadIdx.x;
    int d  = t & (D_INNER - 1);
    int bl = t >> 11;
    int l  = bl & (SEQLEN - 1);

    float4 w = *(const float4*)(cw + d * 4);
    float wk[4] = {w.x, w.y, w.z, w.w};
    float acc = cb[d];

    const float* xx = xz + (size_t)bl * (2 * D_INNER) + d;
    #pragma unroll
    for (int k = 0; k < 4; k++) {
        int ls = l + k - 3;
        if (ls >= 0)
            acc = fmaf(wk[k], xx[(ptrdiff_t)(k - 3) * (2 * D_INNER)], acc);
    }
    u[t] = silu_f(acc);
}

// ---------------------------------------------------------------------------
// Chunked parallel scan, pass 1: per (b,d,chunk) compute the chunk-local
// final state S[16] (zero initial state) and sdt = sum of dt over the chunk.
// s_arr layout: [b][chunk][n][d]  (d innermost -> coalesced)
// ---------------------------------------------------------------------------
__global__ __launch_bounds__(256) void scan_pass1(
    const float* __restrict__ dt, const float* __restrict__ u,
    const float* __restrict__ xdbl, const float* __restrict__ A_log,
    float* __restrict__ s_arr, float* __restrict__ sdt_arr)
{
    int d = blockIdx.x * 256 + threadIdx.x;
    int j = blockIdx.y;
    int b = blockIdx.z;

    float Av[D_STATE];
    #pragma unroll
    for (int n = 0; n < D_STATE; n++)
        Av[n] = -__expf(A_log[d * D_STATE + n]);

    float st[D_STATE] = {};
    float sdt = 0.f;

    size_t idx = ((size_t)(b * SEQLEN + j * CL)) * D_INNER + d;
    const float* xr = xdbl + (size_t)(b * SEQLEN + j * CL) * XPROJ_N + DT_RANK;

    for (int l = 0; l < CL; l++) {
        float dtv = dt[idx];
        float uv  = u[idx];
        float du  = dtv * uv;
        sdt += dtv;
        float4 B0 = *(const float4*)(xr + 0);
        float4 B1 = *(const float4*)(xr + 4);
        float4 B2 = *(const float4*)(xr + 8);
        float4 B3 = *(const float4*)(xr + 12);
        float Bv[16] = {B0.x,B0.y,B0.z,B0.w, B1.x,B1.y,B1.z,B1.w,
                        B2.x,B2.y,B2.z,B2.w, B3.x,B3.y,B3.z,B3.w};
        #pragma unroll
        for (int n = 0; n < D_STATE; n++)
            st[n] = fmaf(st[n], __expf(dtv * Av[n]), du * Bv[n]);
        idx += D_INNER;
        xr  += XPROJ_N;
    }

    size_t base = (size_t)(b * CH + j) * D_STATE * D_INNER + d;
    #pragma unroll
    for (int n = 0; n < D_STATE; n++)
        s_arr[base + (size_t)n * D_INNER] = st[n];
    sdt_arr[(size_t)(b * CH + j) * D_INNER + d] = sdt;
}

// ---------------------------------------------------------------------------
// Pass 2: per (b,d,n) sequentially combine the CH chunk summaries.
// Overwrites s_arr[b][j][n][d] IN PLACE with the state ENTERING chunk j.
// ---------------------------------------------------------------------------
__global__ __launch_bounds__(256) void scan_pass2(
    const float* __restrict__ A_log, const float* __restrict__ sdt_arr,
    float* __restrict__ s_arr)
{
    int t = blockIdx.x * 256 + threadIdx.x;   // 0 .. 65535
    int d = t & (D_INNER - 1);
    int n = (t >> 11) & (D_STATE - 1);
    int b = t >> 15;

    float Av = -__expf(A_log[d * D_STATE + n]);
    float init = 0.f;
    for (int j = 0; j < CH; j++) {
        size_t off = ((size_t)(b * CH + j) * D_STATE + n) * D_INNER + d;
        float sv  = s_arr[off];
        float sdt = sdt_arr[(size_t)(b * CH + j) * D_INNER + d];
        s_arr[off] = init;
        init = fmaf(init, __expf(Av * sdt), sv);
    }
}

// ---------------------------------------------------------------------------
// Pass 3: per (b,d,chunk) rerun the chunk scan with the correct entering
// state and emit y = (sum_n s*C + D*u) * silu(z), in place over dt.
// ---------------------------------------------------------------------------
__global__ __launch_bounds__(256) void scan_pass3(
    const float* __restrict__ dt, const float* __restrict__ u,
    const float* __restrict__ xdbl, const float* __restrict__ xz,
    const float* __restrict__ A_log, const float* __restrict__ Dp,
    const float* __restrict__ s_arr,
    float* __restrict__ y)
{
    int d = blockIdx.x * 256 + threadIdx.x;
    int j = blockIdx.y;
    int b = blockIdx.z;

    float Av[D_STATE];
    #pragma unroll
    for (int n = 0; n < D_STATE; n++)
        Av[n] = -__expf(A_log[d * D_STATE + n]);
    float Dd = Dp[d];

    float st[D_STATE];
    size_t sbase = (size_t)(b * CH + j) * D_STATE * D_INNER + d;
    #pragma unroll
    for (int n = 0; n < D_STATE; n++)
        st[n] = s_arr[sbase + (size_t)n * D_INNER];

    size_t idx  = ((size_t)(b * SEQLEN + j * CL)) * D_INNER + d;
    size_t zidx = ((size_t)(b * SEQLEN + j * CL)) * (2 * D_INNER) + D_INNER + d;
    const float* xr = xdbl + (size_t)(b * SEQLEN + j * CL) * XPROJ_N + DT_RANK;

    for (int l = 0; l < CL; l++) {
        float dtv = dt[idx];
        float uv  = u[idx];
        float du  = dtv * uv;
        float4 B0 = *(const float4*)(xr + 0);
        float4 B1 = *(const float4*)(xr + 4);
        float4 B2 = *(const float4*)(xr + 8);
        float4 B3 = *(const float4*)(xr + 12);
        float4 C0 = *(const float4*)(xr + 16);
        float4 C1 = *(const float4*)(xr + 20);
        float4 C2 = *(const float4*)(xr + 24);
        float4 C3 = *(const float4*)(xr + 28);
        float Bv[16] = {B0.x,B0.y,B0.z,B0.w, B1.x,B1.y,B1.z,B1.w,
                        B2.x,B2.y,B2.z,B2.w, B3.x,B3.y,B3.z,B3.w};
        float Cv[16] = {C0.x,C0.y,C0.z,C0.w, C1.x,C1.y,C1.z,C1.w,
                        C2.x,C2.y,C2.z,C2.w, C3.x,C3.y,C3.z,C3.w};
        float yt = 0.f;
        #pragma unroll
        for (int n = 0; n < D_STATE; n++) {
            float s = fmaf(st[n], __expf(dtv * Av[n]), du * Bv[n]);
            st[n] = s;
            yt = fmaf(s, Cv[n], yt);
        }
        float zv = xz[zidx];
        y[idx] = (yt + Dd * uv) * silu_f(zv);

        idx  += D_INNER;
        zidx += 2 * D_INNER;
        xr   += XPROJ_N;
    }
}

// ---------------------------------------------------------------------------
extern "C" void kernel_launch(void* const* d_in, const int* in_sizes, int n_in,
                              void* d_out, int out_size, void* d_ws, size_t ws_size,
                              hipStream_t stream)
{
    const float* x     = (const float*)d_in[0];
    const float* emb_w = (const float*)d_in[1];
    const float* emb_b = (const float*)d_in[2];
    const float* inw   = (const float*)d_in[3];
    const float* cw    = (const float*)d_in[4];
    const float* cb    = (const float*)d_in[5];
    const float* xpw   = (const float*)d_in[6];
    const float* dtw   = (const float*)d_in[7];
    const float* dtb   = (const float*)d_in[8];
    const float* Alog  = (const float*)d_in[9];
    const float* Dpar  = (const float*)d_in[10];
    const float* outw  = (const float*)d_in[11];

    float* out = (float*)d_out;

    // workspace layout (floats)
    float* ws  = (float*)d_ws;
    float* h   = ws;                    // 2,097,152
    float* xz  = h  + 2097152;          // 8,388,608
    float* u   = xz + 8388608;          // 4,194,304
    float* xd  = u  + 4194304;          //   196,608
    float* dt  = xd + 196608;           // 4,194,304  (y in-place)
    float* sdt = dt + 4194304;          //   131,072  (2*32*2048)
    // chunk-state array aliases h (dead between in_proj and out_proj):
    float* s_arr = h;                   // 2*32*16*2048 = 2,097,152 floats

    embed_kernel<<<(ML * D_MODEL) / 256, 256, 0, stream>>>(x, emb_w, emb_b, h);

    for (int i = 0; i < NUM_BLK; i++) {
        const float* inw_i  = inw  + (size_t)i * (2 * D_INNER) * D_MODEL;
        const float* cw_i   = cw   + (size_t)i * D_INNER * D_CONV;
        const float* cb_i   = cb   + (size_t)i * D_INNER;
        const float* xpw_i  = xpw  + (size_t)i * XPROJ_N * D_INNER;
        const float* dtw_i  = dtw  + (size_t)i * D_INNER * DT_RANK;
        const float* dtb_i  = dtb  + (size_t)i * D_INNER;
        const float* Alog_i = Alog + (size_t)i * D_INNER * D_STATE;
        const float* Dp_i   = Dpar + (size_t)i * D_INNER;
        const float* outw_i = outw + (size_t)i * D_MODEL * D_INNER;

        // xz = h @ in_w^T   (M=2048, N=4096, K=1024)
        gemm_nt<0><<<dim3((2 * D_INNER) / 64, ML / 64), 256, 0, stream>>>(
            h, D_MODEL, inw_i, D_MODEL, nullptr, xz, 2 * D_INNER,
            ML, 2 * D_INNER, D_MODEL);

        // u = silu(conv(xx))
        conv_silu_kernel<<<(ML * D_INNER) / 256, 256, 0, stream>>>(xz, cw_i, cb_i, u);

        // x_dbl = u @ xp_w^T  (M=2048, N=96, K=2048)
        gemm_nt<0><<<dim3((XPROJ_N + 63) / 64, ML / 64), 256, 0, stream>>>(
            u, D_INNER, xpw_i, D_INNER, nullptr, xd, XPROJ_N,
            ML, XPROJ_N, D_INNER);

        // dt = softplus(dt_lo @ dt_w^T + dt_b)  (M=2048, N=2048, K=64)
        gemm_nt<1><<<dim3(D_INNER / 64, ML / 64), 256, 0, stream>>>(
            xd, XPROJ_N, dtw_i, DT_RANK, dtb_i, dt, D_INNER,
            ML, D_INNER, DT_RANK);

        // chunked parallel scan (3 passes); y written in-place over dt
        scan_pass1<<<dim3(D_INNER / 256, CH, BATCH), 256, 0, stream>>>(
            dt, u, xd, Alog_i, s_arr, sdt);
        scan_pass2<<<(BATCH * D_INNER * D_STATE) / 256, 256, 0, stream>>>(
            Alog_i, sdt, s_arr);
        scan_pass3<<<dim3(D_INNER / 256, CH, BATCH), 256, 0, stream>>>(
            dt, u, xd, xz, Alog_i, Dp_i, s_arr, dt);

        // h_next = silu(y @ out_w^T)  (M=2048, N=1024, K=2048)
        float* dst = (i == NUM_BLK - 1) ? out : h;
        gemm_nt<2><<<dim3(D_MODEL / 64, ML / 64), 256, 0, stream>>>(
            dt, D_INNER, outw_i, D_INNER, nullptr, dst, D_MODEL,
            ML, D_MODEL, D_INNER);
    }
}

// Round 3
// 1358.887 us; speedup vs baseline: 4.0510x; 1.7936x over previous
//
#include <hip/hip_runtime.h>
#include <math.h>

#define D_MODEL  1024
#define D_STATE  16
#define D_CONV   4
#define D_INNER  2048
#define DT_RANK  64
#define NUM_BLK  4
#define BATCH    2
#define SEQLEN   1024
#define ML       (BATCH*SEQLEN)   // 2048 rows (b*l flattened)
#define XPROJ_N  (DT_RANK + 2*D_STATE)  // 96
#define CH       32               // chunks per sequence
#define CL       32               // chunk length

typedef __attribute__((ext_vector_type(8))) short short8;
typedef __attribute__((ext_vector_type(4))) float f32x4;

__device__ __forceinline__ float silu_f(float x) {
    return x / (1.0f + __expf(-x));
}
__device__ __forceinline__ float softplus_f(float x) {
    if (x > 15.0f) return x;
    return __logf(1.0f + __expf(x));
}
// bf16 round-to-nearest-even + back
__device__ __forceinline__ unsigned short f2bf(float x) {
    unsigned int u = __float_as_uint(x);
    u += 0x7FFFu + ((u >> 16) & 1u);
    return (unsigned short)(u >> 16);
}
__device__ __forceinline__ float bf2f(unsigned short h) {
    return __uint_as_float(((unsigned int)h) << 16);
}

// ---------------------------------------------------------------------------
// Embedding: writes split-bf16 h pair (h feeds only the MFMA in_proj).
// ---------------------------------------------------------------------------
__global__ __launch_bounds__(256) void embed_kernel(
    const float* __restrict__ x, const float* __restrict__ ew,
    const float* __restrict__ eb,
    unsigned short* __restrict__ h_hi, unsigned short* __restrict__ h_lo)
{
    int t  = blockIdx.x * 256 + threadIdx.x;
    int d  = t & (D_MODEL - 1);
    int bl = t >> 10;
    float v = fmaf(x[bl], ew[d], eb[d]);
    unsigned short h16 = f2bf(v);
    h_hi[t] = h16;
    h_lo[t] = f2bf(v - bf2f(h16));
}

// ---------------------------------------------------------------------------
// fp32 -> (hi,lo) bf16 split, vectorized x4
// ---------------------------------------------------------------------------
__global__ __launch_bounds__(256) void split_bf16_kernel(
    const float* __restrict__ src, unsigned short* __restrict__ hi,
    unsigned short* __restrict__ lo, int n4)
{
    int t = blockIdx.x * 256 + threadIdx.x;
    if (t >= n4) return;
    float4 v = ((const float4*)src)[t];
    ushort4 h, l;
    h.x = f2bf(v.x); l.x = f2bf(v.x - bf2f(h.x));
    h.y = f2bf(v.y); l.y = f2bf(v.y - bf2f(h.y));
    h.z = f2bf(v.z); l.z = f2bf(v.z - bf2f(h.z));
    h.w = f2bf(v.w); l.w = f2bf(v.w - bf2f(h.w));
    ((ushort4*)hi)[t] = h;
    ((ushort4*)lo)[t] = l;
}

// ---------------------------------------------------------------------------
// Split-bf16 MFMA NT GEMM: C[m,n] = act( sum_k A[m,k]*W[n,k] )
// A_hi/A_lo: (MxK) bf16 row-major; W_hi/W_lo: (NxK) bf16 row-major.
// Tile BM x BN, BK=32, 256 threads = 4 waves in 2x2, 16x16x32 MFMA.
// 3-term split: hi*hi + hi*lo + lo*hi (lo*lo ~1e-5 rel, dropped).
// global_load_lds 16B staging (m97 structure). M,N multiples of BM,BN; K of 32.
// EPI: 0 = fp32 store, 1 = silu fp32 store, 2 = silu -> split bf16 pair
// ---------------------------------------------------------------------------
template<int BM, int BN, int EPI>
__global__ __launch_bounds__(256) void mfma_gemm(
    const unsigned short* __restrict__ Ahi, const unsigned short* __restrict__ Alo,
    const unsigned short* __restrict__ Whi, const unsigned short* __restrict__ Wlo,
    float* __restrict__ Cf, unsigned short* __restrict__ Chi,
    unsigned short* __restrict__ Clo,
    int M, int N, int K)
{
    constexpr int MT  = BM / 32;          // 16x16 m-tiles per wave
    constexpr int NT  = BN / 32;
    constexpr int NCH = (BM + BN) / 8;    // 1KB staging chunks per K-tile
    constexpr int CPW = NCH / 4;          // chunks per wave

    __shared__ unsigned short lds[(2*BM + 2*BN) * 32];

    const int tid  = threadIdx.x;
    const int wave = tid >> 6;
    const int lane = tid & 63;
    const int m0 = blockIdx.y * BM;
    const int n0 = blockIdx.x * BN;
    const int wm0 = (wave & 1) * (BM / 2);
    const int wn0 = (wave >> 1) * (BN / 2);
    const int lrow = lane & 15;
    const int kq   = (lane >> 4) * 8;     // k elem offset within 32-tile

    // staging sources: LDS chunk c covers 16 rows (64B each) of one region
    const unsigned short* gsrc[CPW];
    unsigned short* ldst[CPW];
    #pragma unroll
    for (int cc = 0; cc < CPW; cc++) {
        int c  = wave * CPW + cc;
        int r0 = c * 16;
        const unsigned short* s; int row;
        if      (r0 < BM)          { s = Ahi; row = m0 + r0; }
        else if (r0 < 2*BM)        { s = Alo; row = m0 + r0 - BM; }
        else if (r0 < 2*BM + BN)   { s = Whi; row = n0 + r0 - 2*BM; }
        else                       { s = Wlo; row = n0 + r0 - 2*BM - BN; }
        gsrc[cc] = s + (size_t)(row + (lane >> 2)) * K + (lane & 3) * 8;
        ldst[cc] = &lds[c * 512];   // HW adds lane*16B
    }

    f32x4 acc[MT][NT] = {};

    for (int kt = 0; kt < K; kt += 32) {
        __syncthreads();
        #pragma unroll
        for (int cc = 0; cc < CPW; cc++)
            __builtin_amdgcn_global_load_lds(
                (const __attribute__((address_space(1))) unsigned int*)(gsrc[cc] + kt),
                (__attribute__((address_space(3))) unsigned int*)ldst[cc],
                16, 0, 0);
        asm volatile("s_waitcnt vmcnt(0)" ::: "memory");
        __syncthreads();

        short8 ahi[MT], alo[MT], bhi[NT], blo[NT];
        #pragma unroll
        for (int i = 0; i < MT; i++) {
            int r = wm0 + i * 16 + lrow;
            ahi[i] = *(const short8*)&lds[r * 32 + kq];
            alo[i] = *(const short8*)&lds[(BM + r) * 32 + kq];
        }
        #pragma unroll
        for (int j = 0; j < NT; j++) {
            int r = wn0 + j * 16 + lrow;
            bhi[j] = *(const short8*)&lds[(2*BM + r) * 32 + kq];
            blo[j] = *(const short8*)&lds[(2*BM + BN + r) * 32 + kq];
        }
        #pragma unroll
        for (int i = 0; i < MT; i++)
            #pragma unroll
            for (int j = 0; j < NT; j++) {
                acc[i][j] = __builtin_amdgcn_mfma_f32_16x16x32_bf16(ahi[i], bhi[j], acc[i][j], 0, 0, 0);
                acc[i][j] = __builtin_amdgcn_mfma_f32_16x16x32_bf16(ahi[i], blo[j], acc[i][j], 0, 0, 0);
                acc[i][j] = __builtin_amdgcn_mfma_f32_16x16x32_bf16(alo[i], bhi[j], acc[i][j], 0, 0, 0);
            }
    }

    // epilogue: D row = (lane>>4)*4 + reg, col = lane&15  [m89/m91 layout]
    const int orow = (lane >> 4) * 4;
    #pragma unroll
    for (int i = 0; i < MT; i++) {
        #pragma unroll
        for (int j = 0; j < NT; j++) {
            #pragma unroll
            for (int r = 0; r < 4; r++) {
                int gm = m0 + wm0 + i * 16 + orow + r;
                int gn = n0 + wn0 + j * 16 + lrow;
                size_t off = (size_t)gm * N + gn;
                float v = acc[i][j][r];
                if (EPI == 0) {
                    Cf[off] = v;
                } else if (EPI == 1) {
                    Cf[off] = silu_f(v);
                } else {
                    float s = silu_f(v);
                    unsigned short h16 = f2bf(s);
                    Chi[off] = h16;
                    Clo[off] = f2bf(s - bf2f(h16));
                }
            }
        }
    }
}

// ---------------------------------------------------------------------------
// fp32 NT GEMM (kept for xproj / dtproj). +4 pad kills 4-way store conflicts
// while keeping float4 alignment (68 floats = 17 x 16B).
// ---------------------------------------------------------------------------
template <int ACT>
__global__ __launch_bounds__(256) void gemm_nt(
    const float* __restrict__ A, int lda,
    const float* __restrict__ W, int ldw,
    const float* __restrict__ bias,
    float* __restrict__ C, int ldc,
    int M, int N, int K)
{
    const int BM = 64, BN = 64, BK = 16;
    __shared__ float As[BK][BM + 4];
    __shared__ float Ws[BK][BN + 4];

    int tid = threadIdx.x;
    int bx  = blockIdx.x;
    int by  = blockIdx.y;
    int tx  = tid & 15;
    int ty  = tid >> 4;

    int lr = tid >> 2;
    int lk = (tid & 3) * 4;

    int am = by * BM + lr;
    int wn = bx * BN + lr;
    bool wok = (wn < N);

    const float* Ap = A + (size_t)am * lda + lk;
    const float* Wp = wok ? (W + (size_t)wn * ldw + lk) : W;

    float acc[4][4] = {};

    for (int kt = 0; kt < K; kt += BK) {
        float4 av = *(const float4*)(Ap + kt);
        float4 wv = wok ? *(const float4*)(Wp + kt) : make_float4(0.f,0.f,0.f,0.f);

        __syncthreads();
        As[lk+0][lr] = av.x; As[lk+1][lr] = av.y;
        As[lk+2][lr] = av.z; As[lk+3][lr] = av.w;
        Ws[lk+0][lr] = wv.x; Ws[lk+1][lr] = wv.y;
        Ws[lk+2][lr] = wv.z; Ws[lk+3][lr] = wv.w;
        __syncthreads();

        #pragma unroll
        for (int k = 0; k < BK; k++) {
            float4 a = *(const float4*)&As[k][ty*4];
            float4 b = *(const float4*)&Ws[k][tx*4];
            float ar[4] = {a.x, a.y, a.z, a.w};
            float br[4] = {b.x, b.y, b.z, b.w};
            #pragma unroll
            for (int i = 0; i < 4; i++)
                #pragma unroll
                for (int j = 0; j < 4; j++)
                    acc[i][j] = fmaf(ar[i], br[j], acc[i][j]);
        }
    }

    int m0 = by * BM + ty * 4;
    int n0 = bx * BN + tx * 4;
    #pragma unroll
    for (int i = 0; i < 4; i++) {
        #pragma unroll
        for (int j = 0; j < 4; j++) {
            int n = n0 + j;
            if (n < N) {
                float v = acc[i][j];
                if (ACT == 1) v = softplus_f(v + bias[n]);
                C[(size_t)(m0 + i) * ldc + n] = v;
            }
        }
    }
}

// ---------------------------------------------------------------------------
// Causal depthwise conv (width 4) + silu.
// ---------------------------------------------------------------------------
__global__ __launch_bounds__(256) void conv_silu_kernel(
    const float* __restrict__ xz, const float* __restrict__ cw,
    const float* __restrict__ cb, float* __restrict__ u)
{
    int t  = blockIdx.x * 256 + threadIdx.x;
    int d  = t & (D_INNER - 1);
    int bl = t >> 11;
    int l  = bl & (SEQLEN - 1);

    float4 w = *(const float4*)(cw + d * 4);
    float wk[4] = {w.x, w.y, w.z, w.w};
    float acc = cb[d];

    const float* xx = xz + (size_t)bl * (2 * D_INNER) + d;
    #pragma unroll
    for (int k = 0; k < 4; k++) {
        int ls = l + k - 3;
        if (ls >= 0)
            acc = fmaf(wk[k], xx[(ptrdiff_t)(k - 3) * (2 * D_INNER)], acc);
    }
    u[t] = silu_f(acc);
}

// ---------------------------------------------------------------------------
// Chunked parallel scan, pass 1.
// ---------------------------------------------------------------------------
__global__ __launch_bounds__(256) void scan_pass1(
    const float* __restrict__ dt, const float* __restrict__ u,
    const float* __restrict__ xdbl, const float* __restrict__ A_log,
    float* __restrict__ s_arr, float* __restrict__ sdt_arr)
{
    int d = blockIdx.x * 256 + threadIdx.x;
    int j = blockIdx.y;
    int b = blockIdx.z;

    float Av[D_STATE];
    #pragma unroll
    for (int n = 0; n < D_STATE; n++)
        Av[n] = -__expf(A_log[d * D_STATE + n]);

    float st[D_STATE] = {};
    float sdt = 0.f;

    size_t idx = ((size_t)(b * SEQLEN + j * CL)) * D_INNER + d;
    const float* xr = xdbl + (size_t)(b * SEQLEN + j * CL) * XPROJ_N + DT_RANK;

    for (int l = 0; l < CL; l++) {
        float dtv = dt[idx];
        float uv  = u[idx];
        float du  = dtv * uv;
        sdt += dtv;
        float4 B0 = *(const float4*)(xr + 0);
        float4 B1 = *(const float4*)(xr + 4);
        float4 B2 = *(const float4*)(xr + 8);
        float4 B3 = *(const float4*)(xr + 12);
        float Bv[16] = {B0.x,B0.y,B0.z,B0.w, B1.x,B1.y,B1.z,B1.w,
                        B2.x,B2.y,B2.z,B2.w, B3.x,B3.y,B3.z,B3.w};
        #pragma unroll
        for (int n = 0; n < D_STATE; n++)
            st[n] = fmaf(st[n], __expf(dtv * Av[n]), du * Bv[n]);
        idx += D_INNER;
        xr  += XPROJ_N;
    }

    size_t base = (size_t)(b * CH + j) * D_STATE * D_INNER + d;
    #pragma unroll
    for (int n = 0; n < D_STATE; n++)
        s_arr[base + (size_t)n * D_INNER] = st[n];
    sdt_arr[(size_t)(b * CH + j) * D_INNER + d] = sdt;
}

// ---------------------------------------------------------------------------
// Pass 2: combine chunk summaries; s_arr <- entering state per chunk.
// ---------------------------------------------------------------------------
__global__ __launch_bounds__(256) void scan_pass2(
    const float* __restrict__ A_log, const float* __restrict__ sdt_arr,
    float* __restrict__ s_arr)
{
    int t = blockIdx.x * 256 + threadIdx.x;
    int d = t & (D_INNER - 1);
    int n = (t >> 11) & (D_STATE - 1);
    int b = t >> 15;

    float Av = -__expf(A_log[d * D_STATE + n]);
    float init = 0.f;
    for (int j = 0; j < CH; j++) {
        size_t off = ((size_t)(b * CH + j) * D_STATE + n) * D_INNER + d;
        float sv  = s_arr[off];
        float sdt = sdt_arr[(size_t)(b * CH + j) * D_INNER + d];
        s_arr[off] = init;
        init = fmaf(init, __expf(Av * sdt), sv);
    }
}

// ---------------------------------------------------------------------------
// Pass 3: rerun chunks with entering state; y emitted as split-bf16 pair
// (y feeds only the MFMA out_proj).
// ---------------------------------------------------------------------------
__global__ __launch_bounds__(256) void scan_pass3(
    const float* __restrict__ dt, const float* __restrict__ u,
    const float* __restrict__ xdbl, const float* __restrict__ xz,
    const float* __restrict__ A_log, const float* __restrict__ Dp,
    const float* __restrict__ s_arr,
    unsigned short* __restrict__ y_hi, unsigned short* __restrict__ y_lo)
{
    int d = blockIdx.x * 256 + threadIdx.x;
    int j = blockIdx.y;
    int b = blockIdx.z;

    float Av[D_STATE];
    #pragma unroll
    for (int n = 0; n < D_STATE; n++)
        Av[n] = -__expf(A_log[d * D_STATE + n]);
    float Dd = Dp[d];

    float st[D_STATE];
    size_t sbase = (size_t)(b * CH + j) * D_STATE * D_INNER + d;
    #pragma unroll
    for (int n = 0; n < D_STATE; n++)
        st[n] = s_arr[sbase + (size_t)n * D_INNER];

    size_t idx  = ((size_t)(b * SEQLEN + j * CL)) * D_INNER + d;
    size_t zidx = ((size_t)(b * SEQLEN + j * CL)) * (2 * D_INNER) + D_INNER + d;
    const float* xr = xdbl + (size_t)(b * SEQLEN + j * CL) * XPROJ_N + DT_RANK;

    for (int l = 0; l < CL; l++) {
        float dtv = dt[idx];
        float uv  = u[idx];
        float du  = dtv * uv;
        float4 B0 = *(const float4*)(xr + 0);
        float4 B1 = *(const float4*)(xr + 4);
        float4 B2 = *(const float4*)(xr + 8);
        float4 B3 = *(const float4*)(xr + 12);
        float4 C0 = *(const float4*)(xr + 16);
        float4 C1 = *(const float4*)(xr + 20);
        float4 C2 = *(const float4*)(xr + 24);
        float4 C3 = *(const float4*)(xr + 28);
        float Bv[16] = {B0.x,B0.y,B0.z,B0.w, B1.x,B1.y,B1.z,B1.w,
                        B2.x,B2.y,B2.z,B2.w, B3.x,B3.y,B3.z,B3.w};
        float Cv[16] = {C0.x,C0.y,C0.z,C0.w, C1.x,C1.y,C1.z,C1.w,
                        C2.x,C2.y,C2.z,C2.w, C3.x,C3.y,C3.z,C3.w};
        float yt = 0.f;
        #pragma unroll
        for (int n = 0; n < D_STATE; n++) {
            float s = fmaf(st[n], __expf(dtv * Av[n]), du * Bv[n]);
            st[n] = s;
            yt = fmaf(s, Cv[n], yt);
        }
        float zv = xz[zidx];
        float yv = (yt + Dd * uv) * silu_f(zv);
        unsigned short h16 = f2bf(yv);
        y_hi[idx] = h16;
        y_lo[idx] = f2bf(yv - bf2f(h16));

        idx  += D_INNER;
        zidx += 2 * D_INNER;
        xr   += XPROJ_N;
    }
}

// ---------------------------------------------------------------------------
extern "C" void kernel_launch(void* const* d_in, const int* in_sizes, int n_in,
                              void* d_out, int out_size, void* d_ws, size_t ws_size,
                              hipStream_t stream)
{
    const float* x     = (const float*)d_in[0];
    const float* emb_w = (const float*)d_in[1];
    const float* emb_b = (const float*)d_in[2];
    const float* inw   = (const float*)d_in[3];
    const float* cw    = (const float*)d_in[4];
    const float* cb    = (const float*)d_in[5];
    const float* xpw   = (const float*)d_in[6];
    const float* dtw   = (const float*)d_in[7];
    const float* dtb   = (const float*)d_in[8];
    const float* Alog  = (const float*)d_in[9];
    const float* Dpar  = (const float*)d_in[10];
    const float* outw  = (const float*)d_in[11];

    float* out = (float*)d_out;

    // workspace layout
    float* ws    = (float*)d_ws;
    float* xz    = ws;                   // 8,388,608 fl
    float* u     = xz + 8388608;         // 4,194,304 fl
    float* xd    = u  + 4194304;         //   196,608 fl
    float* dt    = xd + 196608;          // 4,194,304 fl
    float* sdt   = dt + 4194304;         //   131,072 fl
    float* s_arr = sdt + 131072;         // 2,097,152 fl
    unsigned short* h_hi = (unsigned short*)(s_arr + 2097152); // 2,097,152 us
    unsigned short* h_lo = h_hi + 2097152;
    unsigned short* y_hi = h_lo + 2097152;                     // 4,194,304 us
    unsigned short* y_lo = y_hi + 4194304;
    unsigned short* wih  = y_lo + 4194304;                     // 4,194,304 us
    unsigned short* wil  = wih + 4194304;
    unsigned short* woh  = wil + 4194304;                      // 2,097,152 us
    unsigned short* wol  = woh + 2097152;
    // total ~127 MB

    embed_kernel<<<(ML * D_MODEL) / 256, 256, 0, stream>>>(x, emb_w, emb_b, h_hi, h_lo);

    for (int i = 0; i < NUM_BLK; i++) {
        const float* inw_i  = inw  + (size_t)i * (2 * D_INNER) * D_MODEL;
        const float* cw_i   = cw   + (size_t)i * D_INNER * D_CONV;
        const float* cb_i   = cb   + (size_t)i * D_INNER;
        const float* xpw_i  = xpw  + (size_t)i * XPROJ_N * D_INNER;
        const float* dtw_i  = dtw  + (size_t)i * D_INNER * DT_RANK;
        const float* dtb_i  = dtb  + (size_t)i * D_INNER;
        const float* Alog_i = Alog + (size_t)i * D_INNER * D_STATE;
        const float* Dp_i   = Dpar + (size_t)i * D_INNER;
        const float* outw_i = outw + (size_t)i * D_MODEL * D_INNER;

        // split in_proj weights (4096x1024)
        split_bf16_kernel<<<4096, 256, 0, stream>>>(inw_i, wih, wil, 1048576);

        // xz = h @ in_w^T  (M=2048, N=4096, K=1024) -- MFMA split-bf16
        mfma_gemm<128, 128, 0><<<dim3(4096 / 128, 2048 / 128), 256, 0, stream>>>(
            h_hi, h_lo, wih, wil, xz, nullptr, nullptr, ML, 2 * D_INNER, D_MODEL);

        // u = silu(conv(xx))
        conv_silu_kernel<<<(ML * D_INNER) / 256, 256, 0, stream>>>(xz, cw_i, cb_i, u);

        // x_dbl = u @ xp_w^T  (M=2048, N=96, K=2048)
        gemm_nt<0><<<dim3((XPROJ_N + 63) / 64, ML / 64), 256, 0, stream>>>(
            u, D_INNER, xpw_i, D_INNER, nullptr, xd, XPROJ_N,
            ML, XPROJ_N, D_INNER);

        // dt = softplus(dt_lo @ dt_w^T + dt_b)  (M=2048, N=2048, K=64)
        gemm_nt<1><<<dim3(D_INNER / 64, ML / 64), 256, 0, stream>>>(
            xd, XPROJ_N, dtw_i, DT_RANK, dtb_i, dt, D_INNER,
            ML, D_INNER, DT_RANK);

        // chunked parallel scan; y emitted as bf16 pair
        scan_pass1<<<dim3(D_INNER / 256, CH, BATCH), 256, 0, stream>>>(
            dt, u, xd, Alog_i, s_arr, sdt);
        scan_pass2<<<(BATCH * D_INNER * D_STATE) / 256, 256, 0, stream>>>(
            Alog_i, sdt, s_arr);
        scan_pass3<<<dim3(D_INNER / 256, CH, BATCH), 256, 0, stream>>>(
            dt, u, xd, xz, Alog_i, Dp_i, s_arr, y_hi, y_lo);

        // split out_proj weights (1024x2048)
        split_bf16_kernel<<<2048, 256, 0, stream>>>(outw_i, woh, wol, 524288);

        // h_next = silu(y @ out_w^T)  (M=2048, N=1024, K=2048) -- MFMA
        if (i == NUM_BLK - 1) {
            mfma_gemm<64, 128, 1><<<dim3(1024 / 128, 2048 / 64), 256, 0, stream>>>(
                y_hi, y_lo, woh, wol, out, nullptr, nullptr, ML, D_MODEL, D_INNER);
        } else {
            mfma_gemm<64, 128, 2><<<dim3(1024 / 128, 2048 / 64), 256, 0, stream>>>(
                y_hi, y_lo, woh, wol, nullptr, h_hi, h_lo, ML, D_MODEL, D_INNER);
        }
    }
}

// Round 4
// 1031.764 us; speedup vs baseline: 5.3354x; 1.3171x over previous
//
#include <hip/hip_runtime.h>
#include <math.h>

#define D_MODEL  1024
#define D_STATE  16
#define D_CONV   4
#define D_INNER  2048
#define DT_RANK  64
#define NUM_BLK  4
#define BATCH    2
#define SEQLEN   1024
#define ML       (BATCH*SEQLEN)   // 2048 rows (b*l flattened)
#define XPROJ_N  (DT_RANK + 2*D_STATE)  // 96
#define CH       32               // chunks per sequence
#define CL       32               // chunk length
#define KSPL     16               // split-K factor for xproj
#define KSEG     (D_INNER / KSPL) // 128

typedef __attribute__((ext_vector_type(8))) short short8;
typedef __attribute__((ext_vector_type(4))) float f32x4;

__device__ __forceinline__ float silu_f(float x) {
    return x / (1.0f + __expf(-x));
}
__device__ __forceinline__ float softplus_f(float x) {
    if (x > 15.0f) return x;
    return __logf(1.0f + __expf(x));
}
// bf16 round-to-nearest-even + back
__device__ __forceinline__ unsigned short f2bf(float x) {
    unsigned int u = __float_as_uint(x);
    u += 0x7FFFu + ((u >> 16) & 1u);
    return (unsigned short)(u >> 16);
}
__device__ __forceinline__ float bf2f(unsigned short h) {
    return __uint_as_float(((unsigned int)h) << 16);
}

// ---------------------------------------------------------------------------
// Embedding: writes split-bf16 h pair (h feeds only the MFMA in_proj).
// ---------------------------------------------------------------------------
__global__ __launch_bounds__(256) void embed_kernel(
    const float* __restrict__ x, const float* __restrict__ ew,
    const float* __restrict__ eb,
    unsigned short* __restrict__ h_hi, unsigned short* __restrict__ h_lo)
{
    int t  = blockIdx.x * 256 + threadIdx.x;
    int d  = t & (D_MODEL - 1);
    int bl = t >> 10;
    float v = fmaf(x[bl], ew[d], eb[d]);
    unsigned short h16 = f2bf(v);
    h_hi[t] = h16;
    h_lo[t] = f2bf(v - bf2f(h16));
}

// ---------------------------------------------------------------------------
// fp32 -> (hi,lo) bf16 split, vectorized x4
// ---------------------------------------------------------------------------
__global__ __launch_bounds__(256) void split_bf16_kernel(
    const float* __restrict__ src, unsigned short* __restrict__ hi,
    unsigned short* __restrict__ lo, int n4)
{
    int t = blockIdx.x * 256 + threadIdx.x;
    if (t >= n4) return;
    float4 v = ((const float4*)src)[t];
    ushort4 h, l;
    h.x = f2bf(v.x); l.x = f2bf(v.x - bf2f(h.x));
    h.y = f2bf(v.y); l.y = f2bf(v.y - bf2f(h.y));
    h.z = f2bf(v.z); l.z = f2bf(v.z - bf2f(h.z));
    h.w = f2bf(v.w); l.w = f2bf(v.w - bf2f(h.w));
    ((ushort4*)hi)[t] = h;
    ((ushort4*)lo)[t] = l;
}

// ---------------------------------------------------------------------------
// Split-bf16 MFMA NT GEMM: C[m,n] = act( sum_k A[m,k]*W[n,k] )
// Tile BM x BN, BK=32, 256 threads = 4 waves in 2x2, 16x16x32 MFMA.
// 3-term split: hi*hi + hi*lo + lo*hi.
// EPI: 0 = fp32 store, 1 = silu fp32 store, 2 = silu -> split bf16 pair
// ---------------------------------------------------------------------------
template<int BM, int BN, int EPI>
__global__ __launch_bounds__(256) void mfma_gemm(
    const unsigned short* __restrict__ Ahi, const unsigned short* __restrict__ Alo,
    const unsigned short* __restrict__ Whi, const unsigned short* __restrict__ Wlo,
    float* __restrict__ Cf, unsigned short* __restrict__ Chi,
    unsigned short* __restrict__ Clo,
    int M, int N, int K)
{
    constexpr int MT  = BM / 32;
    constexpr int NT  = BN / 32;
    constexpr int NCH = (BM + BN) / 8;
    constexpr int CPW = NCH / 4;

    __shared__ unsigned short lds[(2*BM + 2*BN) * 32];

    const int tid  = threadIdx.x;
    const int wave = tid >> 6;
    const int lane = tid & 63;
    const int m0 = blockIdx.y * BM;
    const int n0 = blockIdx.x * BN;
    const int wm0 = (wave & 1) * (BM / 2);
    const int wn0 = (wave >> 1) * (BN / 2);
    const int lrow = lane & 15;
    const int kq   = (lane >> 4) * 8;

    const unsigned short* gsrc[CPW];
    unsigned short* ldst[CPW];
    #pragma unroll
    for (int cc = 0; cc < CPW; cc++) {
        int c  = wave * CPW + cc;
        int r0 = c * 16;
        const unsigned short* s; int row;
        if      (r0 < BM)          { s = Ahi; row = m0 + r0; }
        else if (r0 < 2*BM)        { s = Alo; row = m0 + r0 - BM; }
        else if (r0 < 2*BM + BN)   { s = Whi; row = n0 + r0 - 2*BM; }
        else                       { s = Wlo; row = n0 + r0 - 2*BM - BN; }
        gsrc[cc] = s + (size_t)(row + (lane >> 2)) * K + (lane & 3) * 8;
        ldst[cc] = &lds[c * 512];
    }

    f32x4 acc[MT][NT] = {};

    for (int kt = 0; kt < K; kt += 32) {
        __syncthreads();
        #pragma unroll
        for (int cc = 0; cc < CPW; cc++)
            __builtin_amdgcn_global_load_lds(
                (const __attribute__((address_space(1))) unsigned int*)(gsrc[cc] + kt),
                (__attribute__((address_space(3))) unsigned int*)ldst[cc],
                16, 0, 0);
        asm volatile("s_waitcnt vmcnt(0)" ::: "memory");
        __syncthreads();

        short8 ahi[MT], alo[MT], bhi[NT], blo[NT];
        #pragma unroll
        for (int i = 0; i < MT; i++) {
            int r = wm0 + i * 16 + lrow;
            ahi[i] = *(const short8*)&lds[r * 32 + kq];
            alo[i] = *(const short8*)&lds[(BM + r) * 32 + kq];
        }
        #pragma unroll
        for (int j = 0; j < NT; j++) {
            int r = wn0 + j * 16 + lrow;
            bhi[j] = *(const short8*)&lds[(2*BM + r) * 32 + kq];
            blo[j] = *(const short8*)&lds[(2*BM + BN + r) * 32 + kq];
        }
        #pragma unroll
        for (int i = 0; i < MT; i++)
            #pragma unroll
            for (int j = 0; j < NT; j++) {
                acc[i][j] = __builtin_amdgcn_mfma_f32_16x16x32_bf16(ahi[i], bhi[j], acc[i][j], 0, 0, 0);
                acc[i][j] = __builtin_amdgcn_mfma_f32_16x16x32_bf16(ahi[i], blo[j], acc[i][j], 0, 0, 0);
                acc[i][j] = __builtin_amdgcn_mfma_f32_16x16x32_bf16(alo[i], bhi[j], acc[i][j], 0, 0, 0);
            }
    }

    const int orow = (lane >> 4) * 4;
    #pragma unroll
    for (int i = 0; i < MT; i++) {
        #pragma unroll
        for (int j = 0; j < NT; j++) {
            #pragma unroll
            for (int r = 0; r < 4; r++) {
                int gm = m0 + wm0 + i * 16 + orow + r;
                int gn = n0 + wn0 + j * 16 + lrow;
                size_t off = (size_t)gm * N + gn;
                float v = acc[i][j][r];
                if (EPI == 0) {
                    Cf[off] = v;
                } else if (EPI == 1) {
                    Cf[off] = silu_f(v);
                } else {
                    float s = silu_f(v);
                    unsigned short h16 = f2bf(s);
                    Chi[off] = h16;
                    Clo[off] = f2bf(s - bf2f(h16));
                }
            }
        }
    }
}

// ---------------------------------------------------------------------------
// fp32 NT GEMM (dt_proj only now).
// ---------------------------------------------------------------------------
template <int ACT>
__global__ __launch_bounds__(256) void gemm_nt(
    const float* __restrict__ A, int lda,
    const float* __restrict__ W, int ldw,
    const float* __restrict__ bias,
    float* __restrict__ C, int ldc,
    int M, int N, int K)
{
    const int BM = 64, BN = 64, BK = 16;
    __shared__ float As[BK][BM + 4];
    __shared__ float Ws[BK][BN + 4];

    int tid = threadIdx.x;
    int bx  = blockIdx.x;
    int by  = blockIdx.y;
    int tx  = tid & 15;
    int ty  = tid >> 4;

    int lr = tid >> 2;
    int lk = (tid & 3) * 4;

    int am = by * BM + lr;
    int wn = bx * BN + lr;
    bool wok = (wn < N);

    const float* Ap = A + (size_t)am * lda + lk;
    const float* Wp = wok ? (W + (size_t)wn * ldw + lk) : W;

    float acc[4][4] = {};

    for (int kt = 0; kt < K; kt += BK) {
        float4 av = *(const float4*)(Ap + kt);
        float4 wv = wok ? *(const float4*)(Wp + kt) : make_float4(0.f,0.f,0.f,0.f);

        __syncthreads();
        As[lk+0][lr] = av.x; As[lk+1][lr] = av.y;
        As[lk+2][lr] = av.z; As[lk+3][lr] = av.w;
        Ws[lk+0][lr] = wv.x; Ws[lk+1][lr] = wv.y;
        Ws[lk+2][lr] = wv.z; Ws[lk+3][lr] = wv.w;
        __syncthreads();

        #pragma unroll
        for (int k = 0; k < BK; k++) {
            float4 a = *(const float4*)&As[k][ty*4];
            float4 b = *(const float4*)&Ws[k][tx*4];
            float ar[4] = {a.x, a.y, a.z, a.w};
            float br[4] = {b.x, b.y, b.z, b.w};
            #pragma unroll
            for (int i = 0; i < 4; i++)
                #pragma unroll
                for (int j = 0; j < 4; j++)
                    acc[i][j] = fmaf(ar[i], br[j], acc[i][j]);
        }
    }

    int m0 = by * BM + ty * 4;
    int n0 = bx * BN + tx * 4;
    #pragma unroll
    for (int i = 0; i < 4; i++) {
        #pragma unroll
        for (int j = 0; j < 4; j++) {
            int n = n0 + j;
            if (n < N) {
                float v = acc[i][j];
                if (ACT == 1) v = softplus_f(v + bias[n]);
                C[(size_t)(m0 + i) * ldc + n] = v;
            }
        }
    }
}

// ---------------------------------------------------------------------------
// Split-K xproj: P[kz][m, n] = sum_{k in seg kz} u[m,k]*W[n,k]
// grid (2, M/64, KSPL). Same tile body as gemm_nt.
// ---------------------------------------------------------------------------
__global__ __launch_bounds__(256) void xproj_splitk(
    const float* __restrict__ A,   // u, lda = D_INNER
    const float* __restrict__ W,   // xp_w, ldw = D_INNER
    float* __restrict__ P)         // [KSPL][ML][XPROJ_N]
{
    const int BM = 64, BN = 64, BK = 16;
    __shared__ float As[BK][BM + 4];
    __shared__ float Ws[BK][BN + 4];

    int tid = threadIdx.x;
    int bx  = blockIdx.x;
    int by  = blockIdx.y;
    int kz  = blockIdx.z;
    int tx  = tid & 15;
    int ty  = tid >> 4;

    int lr = tid >> 2;
    int lk = (tid & 3) * 4;

    int am = by * BM + lr;
    int wn = bx * BN + lr;
    bool wok = (wn < XPROJ_N);

    const float* Ap = A + (size_t)am * D_INNER + lk;
    const float* Wp = wok ? (W + (size_t)wn * D_INNER + lk) : W;

    float acc[4][4] = {};

    for (int kt = kz * KSEG; kt < (kz + 1) * KSEG; kt += BK) {
        float4 av = *(const float4*)(Ap + kt);
        float4 wv = wok ? *(const float4*)(Wp + kt) : make_float4(0.f,0.f,0.f,0.f);

        __syncthreads();
        As[lk+0][lr] = av.x; As[lk+1][lr] = av.y;
        As[lk+2][lr] = av.z; As[lk+3][lr] = av.w;
        Ws[lk+0][lr] = wv.x; Ws[lk+1][lr] = wv.y;
        Ws[lk+2][lr] = wv.z; Ws[lk+3][lr] = wv.w;
        __syncthreads();

        #pragma unroll
        for (int k = 0; k < BK; k++) {
            float4 a = *(const float4*)&As[k][ty*4];
            float4 b = *(const float4*)&Ws[k][tx*4];
            float ar[4] = {a.x, a.y, a.z, a.w};
            float br[4] = {b.x, b.y, b.z, b.w};
            #pragma unroll
            for (int i = 0; i < 4; i++)
                #pragma unroll
                for (int j = 0; j < 4; j++)
                    acc[i][j] = fmaf(ar[i], br[j], acc[i][j]);
        }
    }

    float* Pz = P + (size_t)kz * ML * XPROJ_N;
    int m0 = by * BM + ty * 4;
    int n0 = bx * BN + tx * 4;
    #pragma unroll
    for (int i = 0; i < 4; i++) {
        #pragma unroll
        for (int j = 0; j < 4; j++) {
            int n = n0 + j;
            if (n < XPROJ_N)
                Pz[(size_t)(m0 + i) * XPROJ_N + n] = acc[i][j];
        }
    }
}

// ---------------------------------------------------------------------------
// Reduce split-K partials: xd = sum_z P[z]  (vectorized x4)
// ---------------------------------------------------------------------------
__global__ __launch_bounds__(256) void xproj_reduce(
    const float* __restrict__ P, float* __restrict__ xd)
{
    int t = blockIdx.x * 256 + threadIdx.x;   // 0 .. ML*XPROJ_N/4-1
    float4 s = ((const float4*)P)[t];
    #pragma unroll
    for (int z = 1; z < KSPL; z++) {
        float4 v = ((const float4*)(P + (size_t)z * ML * XPROJ_N))[t];
        s.x += v.x; s.y += v.y; s.z += v.z; s.w += v.w;
    }
    ((float4*)xd)[t] = s;
}

// ---------------------------------------------------------------------------
// Causal depthwise conv (width 4) + silu.
// ---------------------------------------------------------------------------
__global__ __launch_bounds__(256) void conv_silu_kernel(
    const float* __restrict__ xz, const float* __restrict__ cw,
    const float* __restrict__ cb, float* __restrict__ u)
{
    int t  = blockIdx.x * 256 + threadIdx.x;
    int d  = t & (D_INNER - 1);
    int bl = t >> 11;
    int l  = bl & (SEQLEN - 1);

    float4 w = *(const float4*)(cw + d * 4);
    float wk[4] = {w.x, w.y, w.z, w.w};
    float acc = cb[d];

    const float* xx = xz + (size_t)bl * (2 * D_INNER) + d;
    #pragma unroll
    for (int k = 0; k < 4; k++) {
        int ls = l + k - 3;
        if (ls >= 0)
            acc = fmaf(wk[k], xx[(ptrdiff_t)(k - 3) * (2 * D_INNER)], acc);
    }
    u[t] = silu_f(acc);
}

// ---------------------------------------------------------------------------
// Chunked parallel scan, pass 1.
// ---------------------------------------------------------------------------
__global__ __launch_bounds__(256) void scan_pass1(
    const float* __restrict__ dt, const float* __restrict__ u,
    const float* __restrict__ xdbl, const float* __restrict__ A_log,
    float* __restrict__ s_arr, float* __restrict__ sdt_arr)
{
    int d = blockIdx.x * 256 + threadIdx.x;
    int j = blockIdx.y;
    int b = blockIdx.z;

    float Av[D_STATE];
    #pragma unroll
    for (int n = 0; n < D_STATE; n++)
        Av[n] = -__expf(A_log[d * D_STATE + n]);

    float st[D_STATE] = {};
    float sdt = 0.f;

    size_t idx = ((size_t)(b * SEQLEN + j * CL)) * D_INNER + d;
    const float* xr = xdbl + (size_t)(b * SEQLEN + j * CL) * XPROJ_N + DT_RANK;

    for (int l = 0; l < CL; l++) {
        float dtv = dt[idx];
        float uv  = u[idx];
        float du  = dtv * uv;
        sdt += dtv;
        float4 B0 = *(const float4*)(xr + 0);
        float4 B1 = *(const float4*)(xr + 4);
        float4 B2 = *(const float4*)(xr + 8);
        float4 B3 = *(const float4*)(xr + 12);
        float Bv[16] = {B0.x,B0.y,B0.z,B0.w, B1.x,B1.y,B1.z,B1.w,
                        B2.x,B2.y,B2.z,B2.w, B3.x,B3.y,B3.z,B3.w};
        #pragma unroll
        for (int n = 0; n < D_STATE; n++)
            st[n] = fmaf(st[n], __expf(dtv * Av[n]), du * Bv[n]);
        idx += D_INNER;
        xr  += XPROJ_N;
    }

    size_t base = (size_t)(b * CH + j) * D_STATE * D_INNER + d;
    #pragma unroll
    for (int n = 0; n < D_STATE; n++)
        s_arr[base + (size_t)n * D_INNER] = st[n];
    sdt_arr[(size_t)(b * CH + j) * D_INNER + d] = sdt;
}

// ---------------------------------------------------------------------------
// Pass 2: combine chunk summaries; s_arr <- entering state per chunk.
// ---------------------------------------------------------------------------
__global__ __launch_bounds__(256) void scan_pass2(
    const float* __restrict__ A_log, const float* __restrict__ sdt_arr,
    float* __restrict__ s_arr)
{
    int t = blockIdx.x * 256 + threadIdx.x;
    int d = t & (D_INNER - 1);
    int n = (t >> 11) & (D_STATE - 1);
    int b = t >> 15;

    float Av = -__expf(A_log[d * D_STATE + n]);
    float init = 0.f;
    for (int j = 0; j < CH; j++) {
        size_t off = ((size_t)(b * CH + j) * D_STATE + n) * D_INNER + d;
        float sv  = s_arr[off];
        float sdt = sdt_arr[(size_t)(b * CH + j) * D_INNER + d];
        s_arr[off] = init;
        init = fmaf(init, __expf(Av * sdt), sv);
    }
}

// ---------------------------------------------------------------------------
// Pass 3: rerun chunks with entering state; y emitted as split-bf16 pair.
// ---------------------------------------------------------------------------
__global__ __launch_bounds__(256) void scan_pass3(
    const float* __restrict__ dt, const float* __restrict__ u,
    const float* __restrict__ xdbl, const float* __restrict__ xz,
    const float* __restrict__ A_log, const float* __restrict__ Dp,
    const float* __restrict__ s_arr,
    unsigned short* __restrict__ y_hi, unsigned short* __restrict__ y_lo)
{
    int d = blockIdx.x * 256 + threadIdx.x;
    int j = blockIdx.y;
    int b = blockIdx.z;

    float Av[D_STATE];
    #pragma unroll
    for (int n = 0; n < D_STATE; n++)
        Av[n] = -__expf(A_log[d * D_STATE + n]);
    float Dd = Dp[d];

    float st[D_STATE];
    size_t sbase = (size_t)(b * CH + j) * D_STATE * D_INNER + d;
    #pragma unroll
    for (int n = 0; n < D_STATE; n++)
        st[n] = s_arr[sbase + (size_t)n * D_INNER];

    size_t idx  = ((size_t)(b * SEQLEN + j * CL)) * D_INNER + d;
    size_t zidx = ((size_t)(b * SEQLEN + j * CL)) * (2 * D_INNER) + D_INNER + d;
    const float* xr = xdbl + (size_t)(b * SEQLEN + j * CL) * XPROJ_N + DT_RANK;

    for (int l = 0; l < CL; l++) {
        float dtv = dt[idx];
        float uv  = u[idx];
        float du  = dtv * uv;
        float4 B0 = *(const float4*)(xr + 0);
        float4 B1 = *(const float4*)(xr + 4);
        float4 B2 = *(const float4*)(xr + 8);
        float4 B3 = *(const float4*)(xr + 12);
        float4 C0 = *(const float4*)(xr + 16);
        float4 C1 = *(const float4*)(xr + 20);
        float4 C2 = *(const float4*)(xr + 24);
        float4 C3 = *(const float4*)(xr + 28);
        float Bv[16] = {B0.x,B0.y,B0.z,B0.w, B1.x,B1.y,B1.z,B1.w,
                        B2.x,B2.y,B2.z,B2.w, B3.x,B3.y,B3.z,B3.w};
        float Cv[16] = {C0.x,C0.y,C0.z,C0.w, C1.x,C1.y,C1.z,C1.w,
                        C2.x,C2.y,C2.z,C2.w, C3.x,C3.y,C3.z,C3.w};
        float yt = 0.f;
        #pragma unroll
        for (int n = 0; n < D_STATE; n++) {
            float s = fmaf(st[n], __expf(dtv * Av[n]), du * Bv[n]);
            st[n] = s;
            yt = fmaf(s, Cv[n], yt);
        }
        float zv = xz[zidx];
        float yv = (yt + Dd * uv) * silu_f(zv);
        unsigned short h16 = f2bf(yv);
        y_hi[idx] = h16;
        y_lo[idx] = f2bf(yv - bf2f(h16));

        idx  += D_INNER;
        zidx += 2 * D_INNER;
        xr   += XPROJ_N;
    }
}

// ---------------------------------------------------------------------------
extern "C" void kernel_launch(void* const* d_in, const int* in_sizes, int n_in,
                              void* d_out, int out_size, void* d_ws, size_t ws_size,
                              hipStream_t stream)
{
    const float* x     = (const float*)d_in[0];
    const float* emb_w = (const float*)d_in[1];
    const float* emb_b = (const float*)d_in[2];
    const float* inw   = (const float*)d_in[3];
    const float* cw    = (const float*)d_in[4];
    const float* cb    = (const float*)d_in[5];
    const float* xpw   = (const float*)d_in[6];
    const float* dtw   = (const float*)d_in[7];
    const float* dtb   = (const float*)d_in[8];
    const float* Alog  = (const float*)d_in[9];
    const float* Dpar  = (const float*)d_in[10];
    const float* outw  = (const float*)d_in[11];

    float* out = (float*)d_out;

    // workspace layout
    float* ws    = (float*)d_ws;
    float* xz    = ws;                   // 8,388,608 fl
    float* u     = xz + 8388608;         // 4,194,304 fl
    float* xd    = u  + 4194304;         //   196,608 fl
    float* dt    = xd + 196608;          // 4,194,304 fl
    float* sdt   = dt + 4194304;         //   131,072 fl
    float* s_arr = sdt + 131072;         // 2,097,152 fl
    float* xpart = s_arr + 2097152;      // KSPL*196,608 = 3,145,728 fl
    unsigned short* h_hi = (unsigned short*)(xpart + (size_t)KSPL * 196608);
    unsigned short* h_lo = h_hi + 2097152;
    unsigned short* y_hi = h_lo + 2097152;
    unsigned short* y_lo = y_hi + 4194304;
    unsigned short* wih  = y_lo + 4194304;
    unsigned short* wil  = wih + 4194304;
    unsigned short* woh  = wil + 4194304;
    unsigned short* wol  = woh + 2097152;
    // total ~140 MB

    embed_kernel<<<(ML * D_MODEL) / 256, 256, 0, stream>>>(x, emb_w, emb_b, h_hi, h_lo);

    for (int i = 0; i < NUM_BLK; i++) {
        const float* inw_i  = inw  + (size_t)i * (2 * D_INNER) * D_MODEL;
        const float* cw_i   = cw   + (size_t)i * D_INNER * D_CONV;
        const float* cb_i   = cb   + (size_t)i * D_INNER;
        const float* xpw_i  = xpw  + (size_t)i * XPROJ_N * D_INNER;
        const float* dtw_i  = dtw  + (size_t)i * D_INNER * DT_RANK;
        const float* dtb_i  = dtb  + (size_t)i * D_INNER;
        const float* Alog_i = Alog + (size_t)i * D_INNER * D_STATE;
        const float* Dp_i   = Dpar + (size_t)i * D_INNER;
        const float* outw_i = outw + (size_t)i * D_MODEL * D_INNER;

        // split in_proj weights (4096x1024)
        split_bf16_kernel<<<4096, 256, 0, stream>>>(inw_i, wih, wil, 1048576);

        // xz = h @ in_w^T  (M=2048, N=4096, K=1024) -- MFMA split-bf16
        mfma_gemm<128, 128, 0><<<dim3(4096 / 128, 2048 / 128), 256, 0, stream>>>(
            h_hi, h_lo, wih, wil, xz, nullptr, nullptr, ML, 2 * D_INNER, D_MODEL);

        // u = silu(conv(xx))
        conv_silu_kernel<<<(ML * D_INNER) / 256, 256, 0, stream>>>(xz, cw_i, cb_i, u);

        // x_dbl = u @ xp_w^T  (M=2048, N=96, K=2048) -- split-K + reduce
        xproj_splitk<<<dim3(2, ML / 64, KSPL), 256, 0, stream>>>(u, xpw_i, xpart);
        xproj_reduce<<<(ML * XPROJ_N / 4) / 256, 256, 0, stream>>>(xpart, xd);

        // dt = softplus(dt_lo @ dt_w^T + dt_b)  (M=2048, N=2048, K=64)
        gemm_nt<1><<<dim3(D_INNER / 64, ML / 64), 256, 0, stream>>>(
            xd, XPROJ_N, dtw_i, DT_RANK, dtb_i, dt, D_INNER,
            ML, D_INNER, DT_RANK);

        // chunked parallel scan; y emitted as bf16 pair
        scan_pass1<<<dim3(D_INNER / 256, CH, BATCH), 256, 0, stream>>>(
            dt, u, xd, Alog_i, s_arr, sdt);
        scan_pass2<<<(BATCH * D_INNER * D_STATE) / 256, 256, 0, stream>>>(
            Alog_i, sdt, s_arr);
        scan_pass3<<<dim3(D_INNER / 256, CH, BATCH), 256, 0, stream>>>(
            dt, u, xd, xz, Alog_i, Dp_i, s_arr, y_hi, y_lo);

        // split out_proj weights (1024x2048)
        split_bf16_kernel<<<2048, 256, 0, stream>>>(outw_i, woh, wol, 524288);

        // h_next = silu(y @ out_w^T)  (M=2048, N=1024, K=2048) -- MFMA
        if (i == NUM_BLK - 1) {
            mfma_gemm<64, 128, 1><<<dim3(1024 / 128, 2048 / 64), 256, 0, stream>>>(
                y_hi, y_lo, woh, wol, out, nullptr, nullptr, ML, D_MODEL, D_INNER);
        } else {
            mfma_gemm<64, 128, 2><<<dim3(1024 / 128, 2048 / 64), 256, 0, stream>>>(
                y_hi, y_lo, woh, wol, nullptr, h_hi, h_lo, ML, D_MODEL, D_INNER);
        }
    }
}

// Round 5
// 943.854 us; speedup vs baseline: 5.8323x; 1.0931x over previous
//
#include <hip/hip_runtime.h>
#include <math.h>

#define D_MODEL  1024
#define D_STATE  16
#define D_CONV   4
#define D_INNER  2048
#define DT_RANK  64
#define NUM_BLK  4
#define BATCH    2
#define SEQLEN   1024
#define ML       (BATCH*SEQLEN)   // 2048 rows (b*l flattened)
#define XPROJ_N  (DT_RANK + 2*D_STATE)  // 96
#define CH       32               // chunks per sequence
#define CL       32               // chunk length
#define KSPL     16               // split-K factor for xproj
#define KSEG     (D_INNER / KSPL) // 128

typedef __attribute__((ext_vector_type(8))) short short8;
typedef __attribute__((ext_vector_type(4))) float f32x4;

__device__ __forceinline__ float silu_f(float x) {
    return x / (1.0f + __expf(-x));
}
__device__ __forceinline__ float softplus_f(float x) {
    if (x > 15.0f) return x;
    return __logf(1.0f + __expf(x));
}
__device__ __forceinline__ unsigned short f2bf(float x) {
    unsigned int u = __float_as_uint(x);
    u += 0x7FFFu + ((u >> 16) & 1u);
    return (unsigned short)(u >> 16);
}
__device__ __forceinline__ float bf2f(unsigned short h) {
    return __uint_as_float(((unsigned int)h) << 16);
}

// ---------------------------------------------------------------------------
// Embedding -> split bf16 pair
// ---------------------------------------------------------------------------
__global__ __launch_bounds__(256) void embed_kernel(
    const float* __restrict__ x, const float* __restrict__ ew,
    const float* __restrict__ eb,
    unsigned short* __restrict__ h_hi, unsigned short* __restrict__ h_lo)
{
    int t  = blockIdx.x * 256 + threadIdx.x;
    int d  = t & (D_MODEL - 1);
    int bl = t >> 10;
    float v = fmaf(x[bl], ew[d], eb[d]);
    unsigned short h16 = f2bf(v);
    h_hi[t] = h16;
    h_lo[t] = f2bf(v - bf2f(h16));
}

// ---------------------------------------------------------------------------
// fp32 -> (hi,lo) bf16 split, vectorized x4
// ---------------------------------------------------------------------------
__global__ __launch_bounds__(256) void split_bf16_kernel(
    const float* __restrict__ src, unsigned short* __restrict__ hi,
    unsigned short* __restrict__ lo, int n4)
{
    int t = blockIdx.x * 256 + threadIdx.x;
    if (t >= n4) return;
    float4 v = ((const float4*)src)[t];
    ushort4 h, l;
    h.x = f2bf(v.x); l.x = f2bf(v.x - bf2f(h.x));
    h.y = f2bf(v.y); l.y = f2bf(v.y - bf2f(h.y));
    h.z = f2bf(v.z); l.z = f2bf(v.z - bf2f(h.z));
    h.w = f2bf(v.w); l.w = f2bf(v.w - bf2f(h.w));
    ((ushort4*)hi)[t] = h;
    ((ushort4*)lo)[t] = l;
}

// ---------------------------------------------------------------------------
// Split-bf16 MFMA NT GEMM. Tile BM x BN, BK=32, WM x WN waves of 64.
// 3-term split: hi*hi + hi*lo + lo*hi.
// EPI: 0 = fp32 store, 1 = silu fp32 store, 2 = silu -> split bf16 pair
// ---------------------------------------------------------------------------
template<int BM, int BN, int WM, int WN, int EPI>
__global__ __launch_bounds__(WM*WN*64) void mfma_gemm(
    const unsigned short* __restrict__ Ahi, const unsigned short* __restrict__ Alo,
    const unsigned short* __restrict__ Whi, const unsigned short* __restrict__ Wlo,
    float* __restrict__ Cf, unsigned short* __restrict__ Chi,
    unsigned short* __restrict__ Clo,
    int M, int N, int K)
{
    constexpr int NW  = WM * WN;
    constexpr int WTM = BM / WM;          // wave tile rows
    constexpr int WTN = BN / WN;          // wave tile cols
    constexpr int MT  = WTM / 16;
    constexpr int NT  = WTN / 16;
    constexpr int NCH = (BM + BN) / 8;    // 1KB staging chunks per K-tile
    constexpr int CPW = NCH / NW;

    __shared__ unsigned short lds[(2*BM + 2*BN) * 32];

    const int tid  = threadIdx.x;
    const int wave = tid >> 6;
    const int lane = tid & 63;
    const int m0 = blockIdx.y * BM;
    const int n0 = blockIdx.x * BN;
    const int wm0 = (wave % WM) * WTM;
    const int wn0 = (wave / WM) * WTN;
    const int lrow = lane & 15;
    const int kq   = (lane >> 4) * 8;

    const unsigned short* gsrc[CPW];
    unsigned short* ldst[CPW];
    #pragma unroll
    for (int cc = 0; cc < CPW; cc++) {
        int c  = wave * CPW + cc;
        int r0 = c * 16;
        const unsigned short* s; int row;
        if      (r0 < BM)          { s = Ahi; row = m0 + r0; }
        else if (r0 < 2*BM)        { s = Alo; row = m0 + r0 - BM; }
        else if (r0 < 2*BM + BN)   { s = Whi; row = n0 + r0 - 2*BM; }
        else                       { s = Wlo; row = n0 + r0 - 2*BM - BN; }
        gsrc[cc] = s + (size_t)(row + (lane >> 2)) * K + (lane & 3) * 8;
        ldst[cc] = &lds[c * 512];
    }

    f32x4 acc[MT][NT] = {};

    for (int kt = 0; kt < K; kt += 32) {
        __syncthreads();
        #pragma unroll
        for (int cc = 0; cc < CPW; cc++)
            __builtin_amdgcn_global_load_lds(
                (const __attribute__((address_space(1))) unsigned int*)(gsrc[cc] + kt),
                (__attribute__((address_space(3))) unsigned int*)ldst[cc],
                16, 0, 0);
        asm volatile("s_waitcnt vmcnt(0)" ::: "memory");
        __syncthreads();

        short8 ahi[MT], alo[MT], bhi[NT], blo[NT];
        #pragma unroll
        for (int i = 0; i < MT; i++) {
            int r = wm0 + i * 16 + lrow;
            ahi[i] = *(const short8*)&lds[r * 32 + kq];
            alo[i] = *(const short8*)&lds[(BM + r) * 32 + kq];
        }
        #pragma unroll
        for (int j = 0; j < NT; j++) {
            int r = wn0 + j * 16 + lrow;
            bhi[j] = *(const short8*)&lds[(2*BM + r) * 32 + kq];
            blo[j] = *(const short8*)&lds[(2*BM + BN + r) * 32 + kq];
        }
        #pragma unroll
        for (int i = 0; i < MT; i++)
            #pragma unroll
            for (int j = 0; j < NT; j++) {
                acc[i][j] = __builtin_amdgcn_mfma_f32_16x16x32_bf16(ahi[i], bhi[j], acc[i][j], 0, 0, 0);
                acc[i][j] = __builtin_amdgcn_mfma_f32_16x16x32_bf16(ahi[i], blo[j], acc[i][j], 0, 0, 0);
                acc[i][j] = __builtin_amdgcn_mfma_f32_16x16x32_bf16(alo[i], bhi[j], acc[i][j], 0, 0, 0);
            }
    }

    const int orow = (lane >> 4) * 4;
    #pragma unroll
    for (int i = 0; i < MT; i++) {
        #pragma unroll
        for (int j = 0; j < NT; j++) {
            #pragma unroll
            for (int r = 0; r < 4; r++) {
                int gm = m0 + wm0 + i * 16 + orow + r;
                int gn = n0 + wn0 + j * 16 + lrow;
                size_t off = (size_t)gm * N + gn;
                float v = acc[i][j][r];
                if (EPI == 0) {
                    Cf[off] = v;
                } else if (EPI == 1) {
                    Cf[off] = silu_f(v);
                } else {
                    float s = silu_f(v);
                    unsigned short h16 = f2bf(s);
                    Chi[off] = h16;
                    Clo[off] = f2bf(s - bf2f(h16));
                }
            }
        }
    }
}

// ---------------------------------------------------------------------------
// fp32 NT GEMM (dt_proj only).
// ---------------------------------------------------------------------------
template <int ACT>
__global__ __launch_bounds__(256) void gemm_nt(
    const float* __restrict__ A, int lda,
    const float* __restrict__ W, int ldw,
    const float* __restrict__ bias,
    float* __restrict__ C, int ldc,
    int M, int N, int K)
{
    const int BM = 64, BN = 64, BK = 16;
    __shared__ float As[BK][BM + 4];
    __shared__ float Ws[BK][BN + 4];

    int tid = threadIdx.x;
    int bx  = blockIdx.x;
    int by  = blockIdx.y;
    int tx  = tid & 15;
    int ty  = tid >> 4;

    int lr = tid >> 2;
    int lk = (tid & 3) * 4;

    int am = by * BM + lr;
    int wn = bx * BN + lr;
    bool wok = (wn < N);

    const float* Ap = A + (size_t)am * lda + lk;
    const float* Wp = wok ? (W + (size_t)wn * ldw + lk) : W;

    float acc[4][4] = {};

    for (int kt = 0; kt < K; kt += BK) {
        float4 av = *(const float4*)(Ap + kt);
        float4 wv = wok ? *(const float4*)(Wp + kt) : make_float4(0.f,0.f,0.f,0.f);

        __syncthreads();
        As[lk+0][lr] = av.x; As[lk+1][lr] = av.y;
        As[lk+2][lr] = av.z; As[lk+3][lr] = av.w;
        Ws[lk+0][lr] = wv.x; Ws[lk+1][lr] = wv.y;
        Ws[lk+2][lr] = wv.z; Ws[lk+3][lr] = wv.w;
        __syncthreads();

        #pragma unroll
        for (int k = 0; k < BK; k++) {
            float4 a = *(const float4*)&As[k][ty*4];
            float4 b = *(const float4*)&Ws[k][tx*4];
            float ar[4] = {a.x, a.y, a.z, a.w};
            float br[4] = {b.x, b.y, b.z, b.w};
            #pragma unroll
            for (int i = 0; i < 4; i++)
                #pragma unroll
                for (int j = 0; j < 4; j++)
                    acc[i][j] = fmaf(ar[i], br[j], acc[i][j]);
        }
    }

    int m0 = by * BM + ty * 4;
    int n0 = bx * BN + tx * 4;
    #pragma unroll
    for (int i = 0; i < 4; i++) {
        #pragma unroll
        for (int j = 0; j < 4; j++) {
            int n = n0 + j;
            if (n < N) {
                float v = acc[i][j];
                if (ACT == 1) v = softplus_f(v + bias[n]);
                C[(size_t)(m0 + i) * ldc + n] = v;
            }
        }
    }
}

// ---------------------------------------------------------------------------
// Split-K xproj with FUSED conv+silu on the A operand:
// u[m,k] = silu(cb[k] + sum_t cw[k,t]*xx[m-3+t, k])  computed on the fly
// from xz (xx = first D_INNER cols of the 2*D_INNER-stride xz rows).
// P[kz][m,n] = sum_{k in seg kz} u[m,k]*W[n,k]
// ---------------------------------------------------------------------------
__global__ __launch_bounds__(256) void xproj_splitk(
    const float* __restrict__ xz, const float* __restrict__ cw,
    const float* __restrict__ cb, const float* __restrict__ W,
    float* __restrict__ P)
{
    const int BM = 64, BN = 64, BK = 16;
    __shared__ float As[BK][BM + 4];
    __shared__ float Ws[BK][BN + 4];

    int tid = threadIdx.x;
    int bx  = blockIdx.x;
    int by  = blockIdx.y;
    int kz  = blockIdx.z;
    int tx  = tid & 15;
    int ty  = tid >> 4;

    int lr = tid >> 2;
    int lk = (tid & 3) * 4;

    int am = by * BM + lr;
    int l  = am & (SEQLEN - 1);
    int wn = bx * BN + lr;
    bool wok = (wn < XPROJ_N);

    const float* Ap3 = xz + (size_t)am * (2 * D_INNER) + lk;  // row am (t=3)
    bool g2 = (l >= 1), g1 = (l >= 2), g0 = (l >= 3);
    const float* Ap2 = Ap3 - (g2 ? 1 : 0) * (2 * D_INNER);
    const float* Ap1 = Ap3 - (g1 ? 2 : 0) * (2 * D_INNER);
    const float* Ap0 = Ap3 - (g0 ? 3 : 0) * (2 * D_INNER);
    const float* Wp  = wok ? (W + (size_t)wn * D_INNER + lk) : W;

    float acc[4][4] = {};

    for (int kt = kz * KSEG; kt < (kz + 1) * KSEG; kt += BK) {
        int k = kt + lk;
        float4 x3 = *(const float4*)(Ap3 + kt);
        float4 x2 = *(const float4*)(Ap2 + kt);
        float4 x1 = *(const float4*)(Ap1 + kt);
        float4 x0 = *(const float4*)(Ap0 + kt);
        if (!g2) x2 = make_float4(0.f,0.f,0.f,0.f);
        if (!g1) x1 = make_float4(0.f,0.f,0.f,0.f);
        if (!g0) x0 = make_float4(0.f,0.f,0.f,0.f);
        float4 c0 = *(const float4*)(cw + (k+0) * 4);
        float4 c1 = *(const float4*)(cw + (k+1) * 4);
        float4 c2 = *(const float4*)(cw + (k+2) * 4);
        float4 c3 = *(const float4*)(cw + (k+3) * 4);
        float4 cbv = *(const float4*)(cb + k);
        float4 av;
        av.x = silu_f(cbv.x + c0.x*x0.x + c0.y*x1.x + c0.z*x2.x + c0.w*x3.x);
        av.y = silu_f(cbv.y + c1.x*x0.y + c1.y*x1.y + c1.z*x2.y + c1.w*x3.y);
        av.z = silu_f(cbv.z + c2.x*x0.z + c2.y*x1.z + c2.z*x2.z + c2.w*x3.z);
        av.w = silu_f(cbv.w + c3.x*x0.w + c3.y*x1.w + c3.z*x2.w + c3.w*x3.w);
        float4 wv = wok ? *(const float4*)(Wp + kt) : make_float4(0.f,0.f,0.f,0.f);

        __syncthreads();
        As[lk+0][lr] = av.x; As[lk+1][lr] = av.y;
        As[lk+2][lr] = av.z; As[lk+3][lr] = av.w;
        Ws[lk+0][lr] = wv.x; Ws[lk+1][lr] = wv.y;
        Ws[lk+2][lr] = wv.z; Ws[lk+3][lr] = wv.w;
        __syncthreads();

        #pragma unroll
        for (int kk = 0; kk < BK; kk++) {
            float4 a = *(const float4*)&As[kk][ty*4];
            float4 b = *(const float4*)&Ws[kk][tx*4];
            float ar[4] = {a.x, a.y, a.z, a.w};
            float br[4] = {b.x, b.y, b.z, b.w};
            #pragma unroll
            for (int i = 0; i < 4; i++)
                #pragma unroll
                for (int j = 0; j < 4; j++)
                    acc[i][j] = fmaf(ar[i], br[j], acc[i][j]);
        }
    }

    float* Pz = P + (size_t)kz * ML * XPROJ_N;
    int m0 = by * BM + ty * 4;
    int n0 = bx * BN + tx * 4;
    #pragma unroll
    for (int i = 0; i < 4; i++) {
        #pragma unroll
        for (int j = 0; j < 4; j++) {
            int n = n0 + j;
            if (n < XPROJ_N)
                Pz[(size_t)(m0 + i) * XPROJ_N + n] = acc[i][j];
        }
    }
}

// ---------------------------------------------------------------------------
// Reduce split-K partials.
// ---------------------------------------------------------------------------
__global__ __launch_bounds__(256) void xproj_reduce(
    const float* __restrict__ P, float* __restrict__ xd)
{
    int t = blockIdx.x * 256 + threadIdx.x;
    float4 s = ((const float4*)P)[t];
    #pragma unroll
    for (int z = 1; z < KSPL; z++) {
        float4 v = ((const float4*)(P + (size_t)z * ML * XPROJ_N))[t];
        s.x += v.x; s.y += v.y; s.z += v.z; s.w += v.w;
    }
    ((float4*)xd)[t] = s;
}

// ---------------------------------------------------------------------------
// Scan pass 1 with FUSED conv+silu (rolling window over xz).
// ---------------------------------------------------------------------------
__global__ __launch_bounds__(256) void scan_pass1(
    const float* __restrict__ dt, const float* __restrict__ xz,
    const float* __restrict__ xdbl, const float* __restrict__ cw,
    const float* __restrict__ cb, const float* __restrict__ A_log,
    float* __restrict__ s_arr, float* __restrict__ sdt_arr)
{
    int d = blockIdx.x * 256 + threadIdx.x;
    int j = blockIdx.y;
    int b = blockIdx.z;

    float Av[D_STATE];
    #pragma unroll
    for (int n = 0; n < D_STATE; n++)
        Av[n] = -__expf(A_log[d * D_STATE + n]);

    float4 cwv = *(const float4*)(cw + d * 4);
    float cbd = cb[d];

    float st[D_STATE] = {};
    float sdt = 0.f;

    size_t idx = ((size_t)(b * SEQLEN + j * CL)) * D_INNER + d;
    size_t xxi = ((size_t)(b * SEQLEN + j * CL)) * (2 * D_INNER) + d;
    const float* xr = xdbl + (size_t)(b * SEQLEN + j * CL) * XPROJ_N + DT_RANK;

    float w0 = 0.f, w1 = 0.f, w2 = 0.f;
    if (j) {
        w0 = xz[xxi - 3 * (2 * D_INNER)];
        w1 = xz[xxi - 2 * (2 * D_INNER)];
        w2 = xz[xxi - 1 * (2 * D_INNER)];
    }

    for (int l = 0; l < CL; l++) {
        float w3 = xz[xxi];
        float uv = silu_f(fmaf(cwv.w, w3, fmaf(cwv.z, w2,
                     fmaf(cwv.y, w1, fmaf(cwv.x, w0, cbd)))));
        float dtv = dt[idx];
        float du  = dtv * uv;
        sdt += dtv;
        float4 B0 = *(const float4*)(xr + 0);
        float4 B1 = *(const float4*)(xr + 4);
        float4 B2 = *(const float4*)(xr + 8);
        float4 B3 = *(const float4*)(xr + 12);
        float Bv[16] = {B0.x,B0.y,B0.z,B0.w, B1.x,B1.y,B1.z,B1.w,
                        B2.x,B2.y,B2.z,B2.w, B3.x,B3.y,B3.z,B3.w};
        #pragma unroll
        for (int n = 0; n < D_STATE; n++)
            st[n] = fmaf(st[n], __expf(dtv * Av[n]), du * Bv[n]);
        w0 = w1; w1 = w2; w2 = w3;
        idx += D_INNER;
        xxi += 2 * D_INNER;
        xr  += XPROJ_N;
    }

    size_t base = (size_t)(b * CH + j) * D_STATE * D_INNER + d;
    #pragma unroll
    for (int n = 0; n < D_STATE; n++)
        s_arr[base + (size_t)n * D_INNER] = st[n];
    sdt_arr[(size_t)(b * CH + j) * D_INNER + d] = sdt;
}

// ---------------------------------------------------------------------------
// Pass 2: combine chunk summaries; s_arr <- entering state per chunk.
// ---------------------------------------------------------------------------
__global__ __launch_bounds__(256) void scan_pass2(
    const float* __restrict__ A_log, const float* __restrict__ sdt_arr,
    float* __restrict__ s_arr)
{
    int t = blockIdx.x * 256 + threadIdx.x;
    int d = t & (D_INNER - 1);
    int n = (t >> 11) & (D_STATE - 1);
    int b = t >> 15;

    float Av = -__expf(A_log[d * D_STATE + n]);
    float init = 0.f;
    for (int j = 0; j < CH; j++) {
        size_t off = ((size_t)(b * CH + j) * D_STATE + n) * D_INNER + d;
        float sv  = s_arr[off];
        float sdt = sdt_arr[(size_t)(b * CH + j) * D_INNER + d];
        s_arr[off] = init;
        init = fmaf(init, __expf(Av * sdt), sv);
    }
}

// ---------------------------------------------------------------------------
// Pass 3 with FUSED conv+silu; y emitted as split-bf16 pair.
// ---------------------------------------------------------------------------
__global__ __launch_bounds__(256) void scan_pass3(
    const float* __restrict__ dt, const float* __restrict__ xz,
    const float* __restrict__ xdbl, const float* __restrict__ cw,
    const float* __restrict__ cb, const float* __restrict__ A_log,
    const float* __restrict__ Dp, const float* __restrict__ s_arr,
    unsigned short* __restrict__ y_hi, unsigned short* __restrict__ y_lo)
{
    int d = blockIdx.x * 256 + threadIdx.x;
    int j = blockIdx.y;
    int b = blockIdx.z;

    float Av[D_STATE];
    #pragma unroll
    for (int n = 0; n < D_STATE; n++)
        Av[n] = -__expf(A_log[d * D_STATE + n]);
    float Dd = Dp[d];
    float4 cwv = *(const float4*)(cw + d * 4);
    float cbd = cb[d];

    float st[D_STATE];
    size_t sbase = (size_t)(b * CH + j) * D_STATE * D_INNER + d;
    #pragma unroll
    for (int n = 0; n < D_STATE; n++)
        st[n] = s_arr[sbase + (size_t)n * D_INNER];

    size_t idx = ((size_t)(b * SEQLEN + j * CL)) * D_INNER + d;
    size_t xxi = ((size_t)(b * SEQLEN + j * CL)) * (2 * D_INNER) + d;
    const float* xr = xdbl + (size_t)(b * SEQLEN + j * CL) * XPROJ_N + DT_RANK;

    float w0 = 0.f, w1 = 0.f, w2 = 0.f;
    if (j) {
        w0 = xz[xxi - 3 * (2 * D_INNER)];
        w1 = xz[xxi - 2 * (2 * D_INNER)];
        w2 = xz[xxi - 1 * (2 * D_INNER)];
    }

    for (int l = 0; l < CL; l++) {
        float w3 = xz[xxi];
        float uv = silu_f(fmaf(cwv.w, w3, fmaf(cwv.z, w2,
                     fmaf(cwv.y, w1, fmaf(cwv.x, w0, cbd)))));
        float dtv = dt[idx];
        float du  = dtv * uv;
        float4 B0 = *(const float4*)(xr + 0);
        float4 B1 = *(const float4*)(xr + 4);
        float4 B2 = *(const float4*)(xr + 8);
        float4 B3 = *(const float4*)(xr + 12);
        float4 C0 = *(const float4*)(xr + 16);
        float4 C1 = *(const float4*)(xr + 20);
        float4 C2 = *(const float4*)(xr + 24);
        float4 C3 = *(const float4*)(xr + 28);
        float Bv[16] = {B0.x,B0.y,B0.z,B0.w, B1.x,B1.y,B1.z,B1.w,
                        B2.x,B2.y,B2.z,B2.w, B3.x,B3.y,B3.z,B3.w};
        float Cv[16] = {C0.x,C0.y,C0.z,C0.w, C1.x,C1.y,C1.z,C1.w,
                        C2.x,C2.y,C2.z,C2.w, C3.x,C3.y,C3.z,C3.w};
        float yt = 0.f;
        #pragma unroll
        for (int n = 0; n < D_STATE; n++) {
            float s = fmaf(st[n], __expf(dtv * Av[n]), du * Bv[n]);
            st[n] = s;
            yt = fmaf(s, Cv[n], yt);
        }
        float zv = xz[xxi + D_INNER];
        float yv = (yt + Dd * uv) * silu_f(zv);
        unsigned short h16 = f2bf(yv);
        y_hi[idx] = h16;
        y_lo[idx] = f2bf(yv - bf2f(h16));

        w0 = w1; w1 = w2; w2 = w3;
        idx += D_INNER;
        xxi += 2 * D_INNER;
        xr  += XPROJ_N;
    }
}

// ---------------------------------------------------------------------------
extern "C" void kernel_launch(void* const* d_in, const int* in_sizes, int n_in,
                              void* d_out, int out_size, void* d_ws, size_t ws_size,
                              hipStream_t stream)
{
    const float* x     = (const float*)d_in[0];
    const float* emb_w = (const float*)d_in[1];
    const float* emb_b = (const float*)d_in[2];
    const float* inw   = (const float*)d_in[3];
    const float* cw    = (const float*)d_in[4];
    const float* cb    = (const float*)d_in[5];
    const float* xpw   = (const float*)d_in[6];
    const float* dtw   = (const float*)d_in[7];
    const float* dtb   = (const float*)d_in[8];
    const float* Alog  = (const float*)d_in[9];
    const float* Dpar  = (const float*)d_in[10];
    const float* outw  = (const float*)d_in[11];

    float* out = (float*)d_out;

    // workspace layout (~123 MB)
    float* ws    = (float*)d_ws;
    float* xz    = ws;                   // 8,388,608 fl
    float* xd    = xz + 8388608;         //   196,608 fl
    float* dt    = xd + 196608;          // 4,194,304 fl
    float* sdt   = dt + 4194304;         //   131,072 fl
    float* s_arr = sdt + 131072;         // 2,097,152 fl
    float* xpart = s_arr + 2097152;      // 3,145,728 fl
    unsigned short* h_hi = (unsigned short*)(xpart + (size_t)KSPL * 196608);
    unsigned short* h_lo = h_hi + 2097152;
    unsigned short* y_hi = h_lo + 2097152;
    unsigned short* y_lo = y_hi + 4194304;
    unsigned short* wih  = y_lo + 4194304;
    unsigned short* wil  = wih + 4194304;
    unsigned short* woh  = wil + 4194304;
    unsigned short* wol  = woh + 2097152;

    embed_kernel<<<(ML * D_MODEL) / 256, 256, 0, stream>>>(x, emb_w, emb_b, h_hi, h_lo);

    for (int i = 0; i < NUM_BLK; i++) {
        const float* inw_i  = inw  + (size_t)i * (2 * D_INNER) * D_MODEL;
        const float* cw_i   = cw   + (size_t)i * D_INNER * D_CONV;
        const float* cb_i   = cb   + (size_t)i * D_INNER;
        const float* xpw_i  = xpw  + (size_t)i * XPROJ_N * D_INNER;
        const float* dtw_i  = dtw  + (size_t)i * D_INNER * DT_RANK;
        const float* dtb_i  = dtb  + (size_t)i * D_INNER;
        const float* Alog_i = Alog + (size_t)i * D_INNER * D_STATE;
        const float* Dp_i   = Dpar + (size_t)i * D_INNER;
        const float* outw_i = outw + (size_t)i * D_MODEL * D_INNER;

        // split in_proj weights (4096x1024)
        split_bf16_kernel<<<4096, 256, 0, stream>>>(inw_i, wih, wil, 1048576);

        // xz = h @ in_w^T  (M=2048, N=4096, K=1024), 512 threads / 8 waves
        mfma_gemm<128, 128, 2, 4, 0><<<dim3(4096 / 128, 2048 / 128), 512, 0, stream>>>(
            h_hi, h_lo, wih, wil, xz, nullptr, nullptr, ML, 2 * D_INNER, D_MODEL);

        // x_dbl = conv-fused u @ xp_w^T  (split-K + reduce)
        xproj_splitk<<<dim3(2, ML / 64, KSPL), 256, 0, stream>>>(
            xz, cw_i, cb_i, xpw_i, xpart);
        xproj_reduce<<<(ML * XPROJ_N / 4) / 256, 256, 0, stream>>>(xpart, xd);

        // dt = softplus(dt_lo @ dt_w^T + dt_b)
        gemm_nt<1><<<dim3(D_INNER / 64, ML / 64), 256, 0, stream>>>(
            xd, XPROJ_N, dtw_i, DT_RANK, dtb_i, dt, D_INNER,
            ML, D_INNER, DT_RANK);

        // chunked parallel scan (conv fused into pass1/pass3)
        scan_pass1<<<dim3(D_INNER / 256, CH, BATCH), 256, 0, stream>>>(
            dt, xz, xd, cw_i, cb_i, Alog_i, s_arr, sdt);
        scan_pass2<<<(BATCH * D_INNER * D_STATE) / 256, 256, 0, stream>>>(
            Alog_i, sdt, s_arr);
        scan_pass3<<<dim3(D_INNER / 256, CH, BATCH), 256, 0, stream>>>(
            dt, xz, xd, cw_i, cb_i, Alog_i, Dp_i, s_arr, y_hi, y_lo);

        // split out_proj weights (1024x2048)
        split_bf16_kernel<<<2048, 256, 0, stream>>>(outw_i, woh, wol, 524288);

        // h_next = silu(y @ out_w^T)  (M=2048, N=1024, K=2048), 64x64 tiles
        if (i == NUM_BLK - 1) {
            mfma_gemm<64, 64, 2, 2, 1><<<dim3(1024 / 64, 2048 / 64), 256, 0, stream>>>(
                y_hi, y_lo, woh, wol, out, nullptr, nullptr, ML, D_MODEL, D_INNER);
        } else {
            mfma_gemm<64, 64, 2, 2, 2><<<dim3(1024 / 64, 2048 / 64), 256, 0, stream>>>(
                y_hi, y_lo, woh, wol, nullptr, h_hi, h_lo, ML, D_MODEL, D_INNER);
        }
    }
}

// Round 6
// 869.805 us; speedup vs baseline: 6.3288x; 1.0851x over previous
//
#include <hip/hip_runtime.h>
#include <math.h>

#define D_MODEL  1024
#define D_STATE  16
#define D_CONV   4
#define D_INNER  2048
#define DT_RANK  64
#define NUM_BLK  4
#define BATCH    2
#define SEQLEN   1024
#define ML       (BATCH*SEQLEN)   // 2048 rows (b*l flattened)
#define XPROJ_N  (DT_RANK + 2*D_STATE)  // 96
#define CH       32               // chunks per sequence
#define CL       32               // chunk length
#define KSPL     16               // split-K factor for xproj
#define KSEG     (D_INNER / KSPL) // 128

typedef __attribute__((ext_vector_type(8))) short short8;
typedef __attribute__((ext_vector_type(4))) float f32x4;

__device__ __forceinline__ float silu_f(float x) {
    return x / (1.0f + __expf(-x));
}
__device__ __forceinline__ float softplus_f(float x) {
    if (x > 15.0f) return x;
    return __logf(1.0f + __expf(x));
}
__device__ __forceinline__ unsigned short f2bf(float x) {
    unsigned int u = __float_as_uint(x);
    u += 0x7FFFu + ((u >> 16) & 1u);
    return (unsigned short)(u >> 16);
}
__device__ __forceinline__ float bf2f(unsigned short h) {
    return __uint_as_float(((unsigned int)h) << 16);
}

// ---------------------------------------------------------------------------
// Embedding -> split bf16 pair
// ---------------------------------------------------------------------------
__global__ __launch_bounds__(256) void embed_kernel(
    const float* __restrict__ x, const float* __restrict__ ew,
    const float* __restrict__ eb,
    unsigned short* __restrict__ h_hi, unsigned short* __restrict__ h_lo)
{
    int t  = blockIdx.x * 256 + threadIdx.x;
    int d  = t & (D_MODEL - 1);
    int bl = t >> 10;
    float v = fmaf(x[bl], ew[d], eb[d]);
    unsigned short h16 = f2bf(v);
    h_hi[t] = h16;
    h_lo[t] = f2bf(v - bf2f(h16));
}

// ---------------------------------------------------------------------------
// fp32 -> bf16 convert (weights; single term), vectorized x4
// ---------------------------------------------------------------------------
__global__ __launch_bounds__(256) void tobf16_kernel(
    const float* __restrict__ src, unsigned short* __restrict__ dst, int n4)
{
    int t = blockIdx.x * 256 + threadIdx.x;
    if (t >= n4) return;
    float4 v = ((const float4*)src)[t];
    ushort4 h;
    h.x = f2bf(v.x); h.y = f2bf(v.y); h.z = f2bf(v.z); h.w = f2bf(v.w);
    ((ushort4*)dst)[t] = h;
}

// ---------------------------------------------------------------------------
// 2-term split-bf16 MFMA NT GEMM: C = act( (Ahi+Alo) @ Whi^T )
// A exact as bf16 hi+lo pair; W single bf16 (rel err ~2^-9, inside 2% budget).
// Tile BM x BN, BK=32, WM x WN waves of 64.
// LDS swizzle: 16B part p of row r stored at granule (p + ((r>>1)&3)) & 3
// within the row's 64B -> read conflicts <=2-way (free).
// EPI: 0 = fp32 store, 1 = silu fp32 store, 2 = silu -> split bf16 pair
// ---------------------------------------------------------------------------
template<int BM, int BN, int WM, int WN, int EPI>
__global__ __launch_bounds__(WM*WN*64) void mfma_gemm(
    const unsigned short* __restrict__ Ahi, const unsigned short* __restrict__ Alo,
    const unsigned short* __restrict__ Whi,
    float* __restrict__ Cf, unsigned short* __restrict__ Chi,
    unsigned short* __restrict__ Clo,
    int M, int N, int K)
{
    constexpr int NW  = WM * WN;
    constexpr int WTM = BM / WM;
    constexpr int WTN = BN / WN;
    constexpr int MT  = WTM / 16;
    constexpr int NT  = WTN / 16;
    constexpr int NCH = (2*BM + BN) / 16;   // 1KB chunks per K-tile
    constexpr int CPW = NCH / NW;

    __shared__ unsigned short lds[(2*BM + BN) * 32];

    const int tid  = threadIdx.x;
    const int wave = tid >> 6;
    const int lane = tid & 63;
    const int m0 = blockIdx.y * BM;
    const int n0 = blockIdx.x * BN;
    const int wm0 = (wave % WM) * WTM;
    const int wn0 = (wave / WM) * WTN;
    const int lrow = lane & 15;
    const int kqi  = lane >> 4;             // k 16B-part index 0..3

    // staging: lane l -> granule l of chunk; holds (row rc = l>>2, part po)
    const int rc = lane >> 2;
    const int po = ((lane & 3) - (rc >> 1)) & 3;

    const unsigned short* gsrc[CPW];
    unsigned short* ldst[CPW];
    #pragma unroll
    for (int cc = 0; cc < CPW; cc++) {
        int c  = wave * CPW + cc;
        int r0 = c * 16;
        const unsigned short* s; int row;
        if      (r0 < BM)        { s = Ahi; row = m0 + r0; }
        else if (r0 < 2*BM)      { s = Alo; row = m0 + r0 - BM; }
        else                     { s = Whi; row = n0 + r0 - 2*BM; }
        gsrc[cc] = s + (size_t)(row + rc) * K + po * 8;
        ldst[cc] = &lds[c * 512];
    }

    f32x4 acc[MT][NT] = {};

    for (int kt = 0; kt < K; kt += 32) {
        __syncthreads();
        #pragma unroll
        for (int cc = 0; cc < CPW; cc++)
            __builtin_amdgcn_global_load_lds(
                (const __attribute__((address_space(1))) unsigned int*)(gsrc[cc] + kt),
                (__attribute__((address_space(3))) unsigned int*)ldst[cc],
                16, 0, 0);
        asm volatile("s_waitcnt vmcnt(0)" ::: "memory");
        __syncthreads();

        short8 ahi[MT], alo[MT], bhi[NT];
        #pragma unroll
        for (int i = 0; i < MT; i++) {
            int r = wm0 + i * 16 + lrow;
            int o = (kqi + ((r >> 1) & 3)) & 3;
            ahi[i] = *(const short8*)&lds[r * 32 + o * 8];
            alo[i] = *(const short8*)&lds[(BM + r) * 32 + o * 8];
        }
        #pragma unroll
        for (int j = 0; j < NT; j++) {
            int r = wn0 + j * 16 + lrow;
            int o = (kqi + ((r >> 1) & 3)) & 3;
            bhi[j] = *(const short8*)&lds[(2*BM + r) * 32 + o * 8];
        }
        #pragma unroll
        for (int i = 0; i < MT; i++)
            #pragma unroll
            for (int j = 0; j < NT; j++) {
                acc[i][j] = __builtin_amdgcn_mfma_f32_16x16x32_bf16(ahi[i], bhi[j], acc[i][j], 0, 0, 0);
                acc[i][j] = __builtin_amdgcn_mfma_f32_16x16x32_bf16(alo[i], bhi[j], acc[i][j], 0, 0, 0);
            }
    }

    const int orow = (lane >> 4) * 4;
    #pragma unroll
    for (int i = 0; i < MT; i++) {
        #pragma unroll
        for (int j = 0; j < NT; j++) {
            #pragma unroll
            for (int r = 0; r < 4; r++) {
                int gm = m0 + wm0 + i * 16 + orow + r;
                int gn = n0 + wn0 + j * 16 + lrow;
                size_t off = (size_t)gm * N + gn;
                float v = acc[i][j][r];
                if (EPI == 0) {
                    Cf[off] = v;
                } else if (EPI == 1) {
                    Cf[off] = silu_f(v);
                } else {
                    float s = silu_f(v);
                    unsigned short h16 = f2bf(s);
                    Chi[off] = h16;
                    Clo[off] = f2bf(s - bf2f(h16));
                }
            }
        }
    }
}

// ---------------------------------------------------------------------------
// fp32 NT GEMM (dt_proj only).
// ---------------------------------------------------------------------------
template <int ACT>
__global__ __launch_bounds__(256) void gemm_nt(
    const float* __restrict__ A, int lda,
    const float* __restrict__ W, int ldw,
    const float* __restrict__ bias,
    float* __restrict__ C, int ldc,
    int M, int N, int K)
{
    const int BM = 64, BN = 64, BK = 16;
    __shared__ float As[BK][BM + 4];
    __shared__ float Ws[BK][BN + 4];

    int tid = threadIdx.x;
    int bx  = blockIdx.x;
    int by  = blockIdx.y;
    int tx  = tid & 15;
    int ty  = tid >> 4;

    int lr = tid >> 2;
    int lk = (tid & 3) * 4;

    int am = by * BM + lr;
    int wn = bx * BN + lr;
    bool wok = (wn < N);

    const float* Ap = A + (size_t)am * lda + lk;
    const float* Wp = wok ? (W + (size_t)wn * ldw + lk) : W;

    float acc[4][4] = {};

    for (int kt = 0; kt < K; kt += BK) {
        float4 av = *(const float4*)(Ap + kt);
        float4 wv = wok ? *(const float4*)(Wp + kt) : make_float4(0.f,0.f,0.f,0.f);

        __syncthreads();
        As[lk+0][lr] = av.x; As[lk+1][lr] = av.y;
        As[lk+2][lr] = av.z; As[lk+3][lr] = av.w;
        Ws[lk+0][lr] = wv.x; Ws[lk+1][lr] = wv.y;
        Ws[lk+2][lr] = wv.z; Ws[lk+3][lr] = wv.w;
        __syncthreads();

        #pragma unroll
        for (int k = 0; k < BK; k++) {
            float4 a = *(const float4*)&As[k][ty*4];
            float4 b = *(const float4*)&Ws[k][tx*4];
            float ar[4] = {a.x, a.y, a.z, a.w};
            float br[4] = {b.x, b.y, b.z, b.w};
            #pragma unroll
            for (int i = 0; i < 4; i++)
                #pragma unroll
                for (int j = 0; j < 4; j++)
                    acc[i][j] = fmaf(ar[i], br[j], acc[i][j]);
        }
    }

    int m0 = by * BM + ty * 4;
    int n0 = bx * BN + tx * 4;
    #pragma unroll
    for (int i = 0; i < 4; i++) {
        #pragma unroll
        for (int j = 0; j < 4; j++) {
            int n = n0 + j;
            if (n < N) {
                float v = acc[i][j];
                if (ACT == 1) v = softplus_f(v + bias[n]);
                C[(size_t)(m0 + i) * ldc + n] = v;
            }
        }
    }
}

// ---------------------------------------------------------------------------
// Split-K xproj with FUSED conv+silu on the A operand.
// ---------------------------------------------------------------------------
__global__ __launch_bounds__(256) void xproj_splitk(
    const float* __restrict__ xz, const float* __restrict__ cw,
    const float* __restrict__ cb, const float* __restrict__ W,
    float* __restrict__ P)
{
    const int BM = 64, BN = 64, BK = 16;
    __shared__ float As[BK][BM + 4];
    __shared__ float Ws[BK][BN + 4];

    int tid = threadIdx.x;
    int bx  = blockIdx.x;
    int by  = blockIdx.y;
    int kz  = blockIdx.z;
    int tx  = tid & 15;
    int ty  = tid >> 4;

    int lr = tid >> 2;
    int lk = (tid & 3) * 4;

    int am = by * BM + lr;
    int l  = am & (SEQLEN - 1);
    int wn = bx * BN + lr;
    bool wok = (wn < XPROJ_N);

    const float* Ap3 = xz + (size_t)am * (2 * D_INNER) + lk;
    bool g2 = (l >= 1), g1 = (l >= 2), g0 = (l >= 3);
    const float* Ap2 = Ap3 - (g2 ? 1 : 0) * (2 * D_INNER);
    const float* Ap1 = Ap3 - (g1 ? 2 : 0) * (2 * D_INNER);
    const float* Ap0 = Ap3 - (g0 ? 3 : 0) * (2 * D_INNER);
    const float* Wp  = wok ? (W + (size_t)wn * D_INNER + lk) : W;

    float acc[4][4] = {};

    for (int kt = kz * KSEG; kt < (kz + 1) * KSEG; kt += BK) {
        int k = kt + lk;
        float4 x3 = *(const float4*)(Ap3 + kt);
        float4 x2 = *(const float4*)(Ap2 + kt);
        float4 x1 = *(const float4*)(Ap1 + kt);
        float4 x0 = *(const float4*)(Ap0 + kt);
        if (!g2) x2 = make_float4(0.f,0.f,0.f,0.f);
        if (!g1) x1 = make_float4(0.f,0.f,0.f,0.f);
        if (!g0) x0 = make_float4(0.f,0.f,0.f,0.f);
        float4 c0 = *(const float4*)(cw + (k+0) * 4);
        float4 c1 = *(const float4*)(cw + (k+1) * 4);
        float4 c2 = *(const float4*)(cw + (k+2) * 4);
        float4 c3 = *(const float4*)(cw + (k+3) * 4);
        float4 cbv = *(const float4*)(cb + k);
        float4 av;
        av.x = silu_f(cbv.x + c0.x*x0.x + c0.y*x1.x + c0.z*x2.x + c0.w*x3.x);
        av.y = silu_f(cbv.y + c1.x*x0.y + c1.y*x1.y + c1.z*x2.y + c1.w*x3.y);
        av.z = silu_f(cbv.z + c2.x*x0.z + c2.y*x1.z + c2.z*x2.z + c2.w*x3.z);
        av.w = silu_f(cbv.w + c3.x*x0.w + c3.y*x1.w + c3.z*x2.w + c3.w*x3.w);
        float4 wv = wok ? *(const float4*)(Wp + kt) : make_float4(0.f,0.f,0.f,0.f);

        __syncthreads();
        As[lk+0][lr] = av.x; As[lk+1][lr] = av.y;
        As[lk+2][lr] = av.z; As[lk+3][lr] = av.w;
        Ws[lk+0][lr] = wv.x; Ws[lk+1][lr] = wv.y;
        Ws[lk+2][lr] = wv.z; Ws[lk+3][lr] = wv.w;
        __syncthreads();

        #pragma unroll
        for (int kk = 0; kk < BK; kk++) {
            float4 a = *(const float4*)&As[kk][ty*4];
            float4 b = *(const float4*)&Ws[kk][tx*4];
            float ar[4] = {a.x, a.y, a.z, a.w};
            float br[4] = {b.x, b.y, b.z, b.w};
            #pragma unroll
            for (int i = 0; i < 4; i++)
                #pragma unroll
                for (int j = 0; j < 4; j++)
                    acc[i][j] = fmaf(ar[i], br[j], acc[i][j]);
        }
    }

    float* Pz = P + (size_t)kz * ML * XPROJ_N;
    int m0 = by * BM + ty * 4;
    int n0 = bx * BN + tx * 4;
    #pragma unroll
    for (int i = 0; i < 4; i++) {
        #pragma unroll
        for (int j = 0; j < 4; j++) {
            int n = n0 + j;
            if (n < XPROJ_N)
                Pz[(size_t)(m0 + i) * XPROJ_N + n] = acc[i][j];
        }
    }
}

// ---------------------------------------------------------------------------
// Reduce split-K partials.
// ---------------------------------------------------------------------------
__global__ __launch_bounds__(256) void xproj_reduce(
    const float* __restrict__ P, float* __restrict__ xd)
{
    int t = blockIdx.x * 256 + threadIdx.x;
    float4 s = ((const float4*)P)[t];
    #pragma unroll
    for (int z = 1; z < KSPL; z++) {
        float4 v = ((const float4*)(P + (size_t)z * ML * XPROJ_N))[t];
        s.x += v.x; s.y += v.y; s.z += v.z; s.w += v.w;
    }
    ((float4*)xd)[t] = s;
}

// ---------------------------------------------------------------------------
// Scan pass 1 with FUSED conv+silu (rolling window over xz).
// ---------------------------------------------------------------------------
__global__ __launch_bounds__(256) void scan_pass1(
    const float* __restrict__ dt, const float* __restrict__ xz,
    const float* __restrict__ xdbl, const float* __restrict__ cw,
    const float* __restrict__ cb, const float* __restrict__ A_log,
    float* __restrict__ s_arr, float* __restrict__ sdt_arr)
{
    int d = blockIdx.x * 256 + threadIdx.x;
    int j = blockIdx.y;
    int b = blockIdx.z;

    float Av[D_STATE];
    #pragma unroll
    for (int n = 0; n < D_STATE; n++)
        Av[n] = -__expf(A_log[d * D_STATE + n]);

    float4 cwv = *(const float4*)(cw + d * 4);
    float cbd = cb[d];

    float st[D_STATE] = {};
    float sdt = 0.f;

    size_t idx = ((size_t)(b * SEQLEN + j * CL)) * D_INNER + d;
    size_t xxi = ((size_t)(b * SEQLEN + j * CL)) * (2 * D_INNER) + d;
    const float* xr = xdbl + (size_t)(b * SEQLEN + j * CL) * XPROJ_N + DT_RANK;

    float w0 = 0.f, w1 = 0.f, w2 = 0.f;
    if (j) {
        w0 = xz[xxi - 3 * (2 * D_INNER)];
        w1 = xz[xxi - 2 * (2 * D_INNER)];
        w2 = xz[xxi - 1 * (2 * D_INNER)];
    }

    for (int l = 0; l < CL; l++) {
        float w3 = xz[xxi];
        float uv = silu_f(fmaf(cwv.w, w3, fmaf(cwv.z, w2,
                     fmaf(cwv.y, w1, fmaf(cwv.x, w0, cbd)))));
        float dtv = dt[idx];
        float du  = dtv * uv;
        sdt += dtv;
        float4 B0 = *(const float4*)(xr + 0);
        float4 B1 = *(const float4*)(xr + 4);
        float4 B2 = *(const float4*)(xr + 8);
        float4 B3 = *(const float4*)(xr + 12);
        float Bv[16] = {B0.x,B0.y,B0.z,B0.w, B1.x,B1.y,B1.z,B1.w,
                        B2.x,B2.y,B2.z,B2.w, B3.x,B3.y,B3.z,B3.w};
        #pragma unroll
        for (int n = 0; n < D_STATE; n++)
            st[n] = fmaf(st[n], __expf(dtv * Av[n]), du * Bv[n]);
        w0 = w1; w1 = w2; w2 = w3;
        idx += D_INNER;
        xxi += 2 * D_INNER;
        xr  += XPROJ_N;
    }

    size_t base = (size_t)(b * CH + j) * D_STATE * D_INNER + d;
    #pragma unroll
    for (int n = 0; n < D_STATE; n++)
        s_arr[base + (size_t)n * D_INNER] = st[n];
    sdt_arr[(size_t)(b * CH + j) * D_INNER + d] = sdt;
}

// ---------------------------------------------------------------------------
// Pass 2: combine chunk summaries; s_arr <- entering state per chunk.
// ---------------------------------------------------------------------------
__global__ __launch_bounds__(256) void scan_pass2(
    const float* __restrict__ A_log, const float* __restrict__ sdt_arr,
    float* __restrict__ s_arr)
{
    int t = blockIdx.x * 256 + threadIdx.x;
    int d = t & (D_INNER - 1);
    int n = (t >> 11) & (D_STATE - 1);
    int b = t >> 15;

    float Av = -__expf(A_log[d * D_STATE + n]);
    float init = 0.f;
    for (int j = 0; j < CH; j++) {
        size_t off = ((size_t)(b * CH + j) * D_STATE + n) * D_INNER + d;
        float sv  = s_arr[off];
        float sdt = sdt_arr[(size_t)(b * CH + j) * D_INNER + d];
        s_arr[off] = init;
        init = fmaf(init, __expf(Av * sdt), sv);
    }
}

// ---------------------------------------------------------------------------
// Pass 3 with FUSED conv+silu; y emitted as split-bf16 pair.
// ---------------------------------------------------------------------------
__global__ __launch_bounds__(256) void scan_pass3(
    const float* __restrict__ dt, const float* __restrict__ xz,
    const float* __restrict__ xdbl, const float* __restrict__ cw,
    const float* __restrict__ cb, const float* __restrict__ A_log,
    const float* __restrict__ Dp, const float* __restrict__ s_arr,
    unsigned short* __restrict__ y_hi, unsigned short* __restrict__ y_lo)
{
    int d = blockIdx.x * 256 + threadIdx.x;
    int j = blockIdx.y;
    int b = blockIdx.z;

    float Av[D_STATE];
    #pragma unroll
    for (int n = 0; n < D_STATE; n++)
        Av[n] = -__expf(A_log[d * D_STATE + n]);
    float Dd = Dp[d];
    float4 cwv = *(const float4*)(cw + d * 4);
    float cbd = cb[d];

    float st[D_STATE];
    size_t sbase = (size_t)(b * CH + j) * D_STATE * D_INNER + d;
    #pragma unroll
    for (int n = 0; n < D_STATE; n++)
        st[n] = s_arr[sbase + (size_t)n * D_INNER];

    size_t idx = ((size_t)(b * SEQLEN + j * CL)) * D_INNER + d;
    size_t xxi = ((size_t)(b * SEQLEN + j * CL)) * (2 * D_INNER) + d;
    const float* xr = xdbl + (size_t)(b * SEQLEN + j * CL) * XPROJ_N + DT_RANK;

    float w0 = 0.f, w1 = 0.f, w2 = 0.f;
    if (j) {
        w0 = xz[xxi - 3 * (2 * D_INNER)];
        w1 = xz[xxi - 2 * (2 * D_INNER)];
        w2 = xz[xxi - 1 * (2 * D_INNER)];
    }

    for (int l = 0; l < CL; l++) {
        float w3 = xz[xxi];
        float uv = silu_f(fmaf(cwv.w, w3, fmaf(cwv.z, w2,
                     fmaf(cwv.y, w1, fmaf(cwv.x, w0, cbd)))));
        float dtv = dt[idx];
        float du  = dtv * uv;
        float4 B0 = *(const float4*)(xr + 0);
        float4 B1 = *(const float4*)(xr + 4);
        float4 B2 = *(const float4*)(xr + 8);
        float4 B3 = *(const float4*)(xr + 12);
        float4 C0 = *(const float4*)(xr + 16);
        float4 C1 = *(const float4*)(xr + 20);
        float4 C2 = *(const float4*)(xr + 24);
        float4 C3 = *(const float4*)(xr + 28);
        float Bv[16] = {B0.x,B0.y,B0.z,B0.w, B1.x,B1.y,B1.z,B1.w,
                        B2.x,B2.y,B2.z,B2.w, B3.x,B3.y,B3.z,B3.w};
        float Cv[16] = {C0.x,C0.y,C0.z,C0.w, C1.x,C1.y,C1.z,C1.w,
                        C2.x,C2.y,C2.z,C2.w, C3.x,C3.y,C3.z,C3.w};
        float yt = 0.f;
        #pragma unroll
        for (int n = 0; n < D_STATE; n++) {
            float s = fmaf(st[n], __expf(dtv * Av[n]), du * Bv[n]);
            st[n] = s;
            yt = fmaf(s, Cv[n], yt);
        }
        float zv = xz[xxi + D_INNER];
        float yv = (yt + Dd * uv) * silu_f(zv);
        unsigned short h16 = f2bf(yv);
        y_hi[idx] = h16;
        y_lo[idx] = f2bf(yv - bf2f(h16));

        w0 = w1; w1 = w2; w2 = w3;
        idx += D_INNER;
        xxi += 2 * D_INNER;
        xr  += XPROJ_N;
    }
}

// ---------------------------------------------------------------------------
extern "C" void kernel_launch(void* const* d_in, const int* in_sizes, int n_in,
                              void* d_out, int out_size, void* d_ws, size_t ws_size,
                              hipStream_t stream)
{
    const float* x     = (const float*)d_in[0];
    const float* emb_w = (const float*)d_in[1];
    const float* emb_b = (const float*)d_in[2];
    const float* inw   = (const float*)d_in[3];
    const float* cw    = (const float*)d_in[4];
    const float* cb    = (const float*)d_in[5];
    const float* xpw   = (const float*)d_in[6];
    const float* dtw   = (const float*)d_in[7];
    const float* dtb   = (const float*)d_in[8];
    const float* Alog  = (const float*)d_in[9];
    const float* Dpar  = (const float*)d_in[10];
    const float* outw  = (const float*)d_in[11];

    float* out = (float*)d_out;

    // workspace layout
    float* ws    = (float*)d_ws;
    float* xz    = ws;                   // 8,388,608 fl
    float* xd    = xz + 8388608;         //   196,608 fl
    float* dt    = xd + 196608;          // 4,194,304 fl
    float* sdt   = dt + 4194304;         //   131,072 fl
    float* s_arr = sdt + 131072;         // 2,097,152 fl
    float* xpart = s_arr + 2097152;      // 3,145,728 fl
    unsigned short* h_hi = (unsigned short*)(xpart + (size_t)KSPL * 196608);
    unsigned short* h_lo = h_hi + 2097152;
    unsigned short* y_hi = h_lo + 2097152;
    unsigned short* y_lo = y_hi + 4194304;
    unsigned short* wih  = y_lo + 4194304;   // 4,194,304 us (in_proj bf16)
    unsigned short* woh  = wih + 4194304;    // 2,097,152 us (out_proj bf16)

    embed_kernel<<<(ML * D_MODEL) / 256, 256, 0, stream>>>(x, emb_w, emb_b, h_hi, h_lo);

    for (int i = 0; i < NUM_BLK; i++) {
        const float* inw_i  = inw  + (size_t)i * (2 * D_INNER) * D_MODEL;
        const float* cw_i   = cw   + (size_t)i * D_INNER * D_CONV;
        const float* cb_i   = cb   + (size_t)i * D_INNER;
        const float* xpw_i  = xpw  + (size_t)i * XPROJ_N * D_INNER;
        const float* dtw_i  = dtw  + (size_t)i * D_INNER * DT_RANK;
        const float* dtb_i  = dtb  + (size_t)i * D_INNER;
        const float* Alog_i = Alog + (size_t)i * D_INNER * D_STATE;
        const float* Dp_i   = Dpar + (size_t)i * D_INNER;
        const float* outw_i = outw + (size_t)i * D_MODEL * D_INNER;

        // in_proj weights -> bf16 (4096x1024)
        tobf16_kernel<<<4096, 256, 0, stream>>>(inw_i, wih, 1048576);

        // xz = h @ in_w^T  (M=2048, N=4096, K=1024), 512 threads / 8 waves
        mfma_gemm<128, 128, 2, 4, 0><<<dim3(4096 / 128, 2048 / 128), 512, 0, stream>>>(
            h_hi, h_lo, wih, xz, nullptr, nullptr, ML, 2 * D_INNER, D_MODEL);

        // x_dbl = conv-fused u @ xp_w^T  (split-K + reduce)
        xproj_splitk<<<dim3(2, ML / 64, KSPL), 256, 0, stream>>>(
            xz, cw_i, cb_i, xpw_i, xpart);
        xproj_reduce<<<(ML * XPROJ_N / 4) / 256, 256, 0, stream>>>(xpart, xd);

        // dt = softplus(dt_lo @ dt_w^T + dt_b)
        gemm_nt<1><<<dim3(D_INNER / 64, ML / 64), 256, 0, stream>>>(
            xd, XPROJ_N, dtw_i, DT_RANK, dtb_i, dt, D_INNER,
            ML, D_INNER, DT_RANK);

        // chunked parallel scan (conv fused into pass1/pass3)
        scan_pass1<<<dim3(D_INNER / 256, CH, BATCH), 256, 0, stream>>>(
            dt, xz, xd, cw_i, cb_i, Alog_i, s_arr, sdt);
        scan_pass2<<<(BATCH * D_INNER * D_STATE) / 256, 256, 0, stream>>>(
            Alog_i, sdt, s_arr);
        scan_pass3<<<dim3(D_INNER / 256, CH, BATCH), 256, 0, stream>>>(
            dt, xz, xd, cw_i, cb_i, Alog_i, Dp_i, s_arr, y_hi, y_lo);

        // out_proj weights -> bf16 (1024x2048)
        tobf16_kernel<<<2048, 256, 0, stream>>>(outw_i, woh, 524288);

        // h_next = silu(y @ out_w^T)  (M=2048, N=1024, K=2048), 64x128 tiles
        if (i == NUM_BLK - 1) {
            mfma_gemm<64, 128, 2, 4, 1><<<dim3(1024 / 128, 2048 / 64), 512, 0, stream>>>(
                y_hi, y_lo, woh, out, nullptr, nullptr, ML, D_MODEL, D_INNER);
        } else {
            mfma_gemm<64, 128, 2, 4, 2><<<dim3(1024 / 128, 2048 / 64), 512, 0, stream>>>(
                y_hi, y_lo, woh, nullptr, h_hi, h_lo, ML, D_MODEL, D_INNER);
        }
    }
}

// Round 7
// 832.580 us; speedup vs baseline: 6.6118x; 1.0447x over previous
//
#include <hip/hip_runtime.h>
#include <math.h>

#define D_MODEL  1024
#define D_STATE  16
#define D_CONV   4
#define D_INNER  2048
#define DT_RANK  64
#define NUM_BLK  4
#define BATCH    2
#define SEQLEN   1024
#define ML       (BATCH*SEQLEN)   // 2048 rows (b*l flattened)
#define XPROJ_N  (DT_RANK + 2*D_STATE)  // 96
#define CH       32               // chunks per sequence
#define CL       32               // chunk length
#define KSPL     16               // split-K factor for xproj
#define KSEG     (D_INNER / KSPL) // 128

typedef __attribute__((ext_vector_type(8))) short short8;
typedef __attribute__((ext_vector_type(4))) float f32x4;

__device__ __forceinline__ float silu_f(float x) {
    return x / (1.0f + __expf(-x));
}
__device__ __forceinline__ float softplus_f(float x) {
    if (x > 15.0f) return x;
    return __logf(1.0f + __expf(x));
}
__device__ __forceinline__ unsigned short f2bf(float x) {
    unsigned int u = __float_as_uint(x);
    u += 0x7FFFu + ((u >> 16) & 1u);
    return (unsigned short)(u >> 16);
}
__device__ __forceinline__ float bf2f(unsigned short h) {
    return __uint_as_float(((unsigned int)h) << 16);
}

// ---------------------------------------------------------------------------
// Embedding -> split bf16 pair
// ---------------------------------------------------------------------------
__global__ __launch_bounds__(256) void embed_kernel(
    const float* __restrict__ x, const float* __restrict__ ew,
    const float* __restrict__ eb,
    unsigned short* __restrict__ h_hi, unsigned short* __restrict__ h_lo)
{
    int t  = blockIdx.x * 256 + threadIdx.x;
    int d  = t & (D_MODEL - 1);
    int bl = t >> 10;
    float v = fmaf(x[bl], ew[d], eb[d]);
    unsigned short h16 = f2bf(v);
    h_hi[t] = h16;
    h_lo[t] = f2bf(v - bf2f(h16));
}

// ---------------------------------------------------------------------------
// fp32 -> bf16 convert (bulk weights), vectorized x4
// ---------------------------------------------------------------------------
__global__ __launch_bounds__(256) void tobf16_kernel(
    const float* __restrict__ src, unsigned short* __restrict__ dst, int n4)
{
    int t = blockIdx.x * 256 + threadIdx.x;
    if (t >= n4) return;
    float4 v = ((const float4*)src)[t];
    ushort4 h;
    h.x = f2bf(v.x); h.y = f2bf(v.y); h.z = f2bf(v.z); h.w = f2bf(v.w);
    ((ushort4*)dst)[t] = h;
}

// ---------------------------------------------------------------------------
// 2-term split-bf16 MFMA NT GEMM: C = act( (Ahi+Alo) @ Whi^T )
// LDS swizzle: 16B part p of row r stored at granule (p + ((r>>1)&3)) & 3.
// KSPLIT>1: blockIdx.z selects K-segment; raw fp32 partial written to
// Cf + z*M*N (EPI ignored).
// EPI: 0 = fp32 store, 1 = silu fp32, 2 = silu -> split bf16 pair
// ---------------------------------------------------------------------------
template<int BM, int BN, int WM, int WN, int EPI, int KSPLIT>
__global__ __launch_bounds__(WM*WN*64) void mfma_gemm(
    const unsigned short* __restrict__ Ahi, const unsigned short* __restrict__ Alo,
    const unsigned short* __restrict__ Whi,
    float* __restrict__ Cf, unsigned short* __restrict__ Chi,
    unsigned short* __restrict__ Clo,
    int M, int N, int K)
{
    constexpr int NW  = WM * WN;
    constexpr int WTM = BM / WM;
    constexpr int WTN = BN / WN;
    constexpr int MT  = WTM / 16;
    constexpr int NT  = WTN / 16;
    constexpr int NCH = (2*BM + BN) / 16;   // 1KB chunks per K-tile
    constexpr int CPW = NCH / NW;

    __shared__ unsigned short lds[(2*BM + BN) * 32];

    const int tid  = threadIdx.x;
    const int wave = tid >> 6;
    const int lane = tid & 63;
    const int m0 = blockIdx.y * BM;
    const int n0 = blockIdx.x * BN;
    const int wm0 = (wave % WM) * WTM;
    const int wn0 = (wave / WM) * WTN;
    const int lrow = lane & 15;
    const int kqi  = lane >> 4;             // k 16B-part index 0..3

    const int rc = lane >> 2;
    const int po = ((lane & 3) - (rc >> 1)) & 3;

    const unsigned short* gsrc[CPW];
    unsigned short* ldst[CPW];
    #pragma unroll
    for (int cc = 0; cc < CPW; cc++) {
        int c  = wave * CPW + cc;
        int r0 = c * 16;
        const unsigned short* s; int row;
        if      (r0 < BM)        { s = Ahi; row = m0 + r0; }
        else if (r0 < 2*BM)      { s = Alo; row = m0 + r0 - BM; }
        else                     { s = Whi; row = n0 + r0 - 2*BM; }
        gsrc[cc] = s + (size_t)(row + rc) * K + po * 8;
        ldst[cc] = &lds[c * 512];
    }

    f32x4 acc[MT][NT] = {};

    const int kseg = K / KSPLIT;
    const int kz   = (KSPLIT > 1) ? blockIdx.z : 0;
    const int kbeg = kz * kseg;
    const int kend = kbeg + kseg;

    for (int kt = kbeg; kt < kend; kt += 32) {
        __syncthreads();
        #pragma unroll
        for (int cc = 0; cc < CPW; cc++)
            __builtin_amdgcn_global_load_lds(
                (const __attribute__((address_space(1))) unsigned int*)(gsrc[cc] + kt),
                (__attribute__((address_space(3))) unsigned int*)ldst[cc],
                16, 0, 0);
        asm volatile("s_waitcnt vmcnt(0)" ::: "memory");
        __syncthreads();

        short8 ahi[MT], alo[MT], bhi[NT];
        #pragma unroll
        for (int i = 0; i < MT; i++) {
            int r = wm0 + i * 16 + lrow;
            int o = (kqi + ((r >> 1) & 3)) & 3;
            ahi[i] = *(const short8*)&lds[r * 32 + o * 8];
            alo[i] = *(const short8*)&lds[(BM + r) * 32 + o * 8];
        }
        #pragma unroll
        for (int j = 0; j < NT; j++) {
            int r = wn0 + j * 16 + lrow;
            int o = (kqi + ((r >> 1) & 3)) & 3;
            bhi[j] = *(const short8*)&lds[(2*BM + r) * 32 + o * 8];
        }
        #pragma unroll
        for (int i = 0; i < MT; i++)
            #pragma unroll
            for (int j = 0; j < NT; j++) {
                acc[i][j] = __builtin_amdgcn_mfma_f32_16x16x32_bf16(ahi[i], bhi[j], acc[i][j], 0, 0, 0);
                acc[i][j] = __builtin_amdgcn_mfma_f32_16x16x32_bf16(alo[i], bhi[j], acc[i][j], 0, 0, 0);
            }
    }

    const int orow = (lane >> 4) * 4;
    float* Cfz = Cf + (KSPLIT > 1 ? (size_t)kz * M * N : 0);
    #pragma unroll
    for (int i = 0; i < MT; i++) {
        #pragma unroll
        for (int j = 0; j < NT; j++) {
            #pragma unroll
            for (int r = 0; r < 4; r++) {
                int gm = m0 + wm0 + i * 16 + orow + r;
                int gn = n0 + wn0 + j * 16 + lrow;
                size_t off = (size_t)gm * N + gn;
                float v = acc[i][j][r];
                if (KSPLIT > 1 || EPI == 0) {
                    Cfz[off] = v;
                } else if (EPI == 1) {
                    Cf[off] = silu_f(v);
                } else {
                    float s = silu_f(v);
                    unsigned short h16 = f2bf(s);
                    Chi[off] = h16;
                    Clo[off] = f2bf(s - bf2f(h16));
                }
            }
        }
    }
}

// ---------------------------------------------------------------------------
// out_proj split-K reduce: sum 2 partial planes, silu, emit.
// FINAL=1 -> fp32 to out; FINAL=0 -> split bf16 pair (next block's h).
// ---------------------------------------------------------------------------
template<int FINAL>
__global__ __launch_bounds__(256) void oproj_reduce(
    const float* __restrict__ P, float* __restrict__ outf,
    unsigned short* __restrict__ hi, unsigned short* __restrict__ lo)
{
    const int MN4 = ML * D_MODEL / 4;
    int t = blockIdx.x * 256 + threadIdx.x;   // 0 .. MN4-1
    float4 a = ((const float4*)P)[t];
    float4 b = ((const float4*)(P + (size_t)ML * D_MODEL))[t];
    float4 s;
    s.x = silu_f(a.x + b.x); s.y = silu_f(a.y + b.y);
    s.z = silu_f(a.z + b.z); s.w = silu_f(a.w + b.w);
    if (FINAL) {
        ((float4*)outf)[t] = s;
    } else {
        ushort4 h, l;
        h.x = f2bf(s.x); l.x = f2bf(s.x - bf2f(h.x));
        h.y = f2bf(s.y); l.y = f2bf(s.y - bf2f(h.y));
        h.z = f2bf(s.z); l.z = f2bf(s.z - bf2f(h.z));
        h.w = f2bf(s.w); l.w = f2bf(s.w - bf2f(h.w));
        ((ushort4*)hi)[t] = h;
        ((ushort4*)lo)[t] = l;
    }
}

// ---------------------------------------------------------------------------
// fp32 NT GEMM (dt_proj only).
// ---------------------------------------------------------------------------
template <int ACT>
__global__ __launch_bounds__(256) void gemm_nt(
    const float* __restrict__ A, int lda,
    const float* __restrict__ W, int ldw,
    const float* __restrict__ bias,
    float* __restrict__ C, int ldc,
    int M, int N, int K)
{
    const int BM = 64, BN = 64, BK = 16;
    __shared__ float As[BK][BM + 4];
    __shared__ float Ws[BK][BN + 4];

    int tid = threadIdx.x;
    int bx  = blockIdx.x;
    int by  = blockIdx.y;
    int tx  = tid & 15;
    int ty  = tid >> 4;

    int lr = tid >> 2;
    int lk = (tid & 3) * 4;

    int am = by * BM + lr;
    int wn = bx * BN + lr;
    bool wok = (wn < N);

    const float* Ap = A + (size_t)am * lda + lk;
    const float* Wp = wok ? (W + (size_t)wn * ldw + lk) : W;

    float acc[4][4] = {};

    for (int kt = 0; kt < K; kt += BK) {
        float4 av = *(const float4*)(Ap + kt);
        float4 wv = wok ? *(const float4*)(Wp + kt) : make_float4(0.f,0.f,0.f,0.f);

        __syncthreads();
        As[lk+0][lr] = av.x; As[lk+1][lr] = av.y;
        As[lk+2][lr] = av.z; As[lk+3][lr] = av.w;
        Ws[lk+0][lr] = wv.x; Ws[lk+1][lr] = wv.y;
        Ws[lk+2][lr] = wv.z; Ws[lk+3][lr] = wv.w;
        __syncthreads();

        #pragma unroll
        for (int k = 0; k < BK; k++) {
            float4 a = *(const float4*)&As[k][ty*4];
            float4 b = *(const float4*)&Ws[k][tx*4];
            float ar[4] = {a.x, a.y, a.z, a.w};
            float br[4] = {b.x, b.y, b.z, b.w};
            #pragma unroll
            for (int i = 0; i < 4; i++)
                #pragma unroll
                for (int j = 0; j < 4; j++)
                    acc[i][j] = fmaf(ar[i], br[j], acc[i][j]);
        }
    }

    int m0 = by * BM + ty * 4;
    int n0 = bx * BN + tx * 4;
    #pragma unroll
    for (int i = 0; i < 4; i++) {
        #pragma unroll
        for (int j = 0; j < 4; j++) {
            int n = n0 + j;
            if (n < N) {
                float v = acc[i][j];
                if (ACT == 1) v = softplus_f(v + bias[n]);
                C[(size_t)(m0 + i) * ldc + n] = v;
            }
        }
    }
}

// ---------------------------------------------------------------------------
// Split-K xproj with FUSED conv+silu on the A operand.
// ---------------------------------------------------------------------------
__global__ __launch_bounds__(256) void xproj_splitk(
    const float* __restrict__ xz, const float* __restrict__ cw,
    const float* __restrict__ cb, const float* __restrict__ W,
    float* __restrict__ P)
{
    const int BM = 64, BN = 64, BK = 16;
    __shared__ float As[BK][BM + 4];
    __shared__ float Ws[BK][BN + 4];

    int tid = threadIdx.x;
    int bx  = blockIdx.x;
    int by  = blockIdx.y;
    int kz  = blockIdx.z;
    int tx  = tid & 15;
    int ty  = tid >> 4;

    int lr = tid >> 2;
    int lk = (tid & 3) * 4;

    int am = by * BM + lr;
    int l  = am & (SEQLEN - 1);
    int wn = bx * BN + lr;
    bool wok = (wn < XPROJ_N);

    const float* Ap3 = xz + (size_t)am * (2 * D_INNER) + lk;
    bool g2 = (l >= 1), g1 = (l >= 2), g0 = (l >= 3);
    const float* Ap2 = Ap3 - (g2 ? 1 : 0) * (2 * D_INNER);
    const float* Ap1 = Ap3 - (g1 ? 2 : 0) * (2 * D_INNER);
    const float* Ap0 = Ap3 - (g0 ? 3 : 0) * (2 * D_INNER);
    const float* Wp  = wok ? (W + (size_t)wn * D_INNER + lk) : W;

    float acc[4][4] = {};

    for (int kt = kz * KSEG; kt < (kz + 1) * KSEG; kt += BK) {
        int k = kt + lk;
        float4 x3 = *(const float4*)(Ap3 + kt);
        float4 x2 = *(const float4*)(Ap2 + kt);
        float4 x1 = *(const float4*)(Ap1 + kt);
        float4 x0 = *(const float4*)(Ap0 + kt);
        if (!g2) x2 = make_float4(0.f,0.f,0.f,0.f);
        if (!g1) x1 = make_float4(0.f,0.f,0.f,0.f);
        if (!g0) x0 = make_float4(0.f,0.f,0.f,0.f);
        float4 c0 = *(const float4*)(cw + (k+0) * 4);
        float4 c1 = *(const float4*)(cw + (k+1) * 4);
        float4 c2 = *(const float4*)(cw + (k+2) * 4);
        float4 c3 = *(const float4*)(cw + (k+3) * 4);
        float4 cbv = *(const float4*)(cb + k);
        float4 av;
        av.x = silu_f(cbv.x + c0.x*x0.x + c0.y*x1.x + c0.z*x2.x + c0.w*x3.x);
        av.y = silu_f(cbv.y + c1.x*x0.y + c1.y*x1.y + c1.z*x2.y + c1.w*x3.y);
        av.z = silu_f(cbv.z + c2.x*x0.z + c2.y*x1.z + c2.z*x2.z + c2.w*x3.z);
        av.w = silu_f(cbv.w + c3.x*x0.w + c3.y*x1.w + c3.z*x2.w + c3.w*x3.w);
        float4 wv = wok ? *(const float4*)(Wp + kt) : make_float4(0.f,0.f,0.f,0.f);

        __syncthreads();
        As[lk+0][lr] = av.x; As[lk+1][lr] = av.y;
        As[lk+2][lr] = av.z; As[lk+3][lr] = av.w;
        Ws[lk+0][lr] = wv.x; Ws[lk+1][lr] = wv.y;
        Ws[lk+2][lr] = wv.z; Ws[lk+3][lr] = wv.w;
        __syncthreads();

        #pragma unroll
        for (int kk = 0; kk < BK; kk++) {
            float4 a = *(const float4*)&As[kk][ty*4];
            float4 b = *(const float4*)&Ws[kk][tx*4];
            float ar[4] = {a.x, a.y, a.z, a.w};
            float br[4] = {b.x, b.y, b.z, b.w};
            #pragma unroll
            for (int i = 0; i < 4; i++)
                #pragma unroll
                for (int j = 0; j < 4; j++)
                    acc[i][j] = fmaf(ar[i], br[j], acc[i][j]);
        }
    }

    float* Pz = P + (size_t)kz * ML * XPROJ_N;
    int m0 = by * BM + ty * 4;
    int n0 = bx * BN + tx * 4;
    #pragma unroll
    for (int i = 0; i < 4; i++) {
        #pragma unroll
        for (int j = 0; j < 4; j++) {
            int n = n0 + j;
            if (n < XPROJ_N)
                Pz[(size_t)(m0 + i) * XPROJ_N + n] = acc[i][j];
        }
    }
}

// ---------------------------------------------------------------------------
// Reduce split-K partials (xproj).
// ---------------------------------------------------------------------------
__global__ __launch_bounds__(256) void xproj_reduce(
    const float* __restrict__ P, float* __restrict__ xd)
{
    int t = blockIdx.x * 256 + threadIdx.x;
    float4 s = ((const float4*)P)[t];
    #pragma unroll
    for (int z = 1; z < KSPL; z++) {
        float4 v = ((const float4*)(P + (size_t)z * ML * XPROJ_N))[t];
        s.x += v.x; s.y += v.y; s.z += v.z; s.w += v.w;
    }
    ((float4*)xd)[t] = s;
}

// ---------------------------------------------------------------------------
// Scan pass 1 with FUSED conv+silu (rolling window over xz).
// ---------------------------------------------------------------------------
__global__ __launch_bounds__(256) void scan_pass1(
    const float* __restrict__ dt, const float* __restrict__ xz,
    const float* __restrict__ xdbl, const float* __restrict__ cw,
    const float* __restrict__ cb, const float* __restrict__ A_log,
    float* __restrict__ s_arr, float* __restrict__ sdt_arr)
{
    int d = blockIdx.x * 256 + threadIdx.x;
    int j = blockIdx.y;
    int b = blockIdx.z;

    float Av[D_STATE];
    #pragma unroll
    for (int n = 0; n < D_STATE; n++)
        Av[n] = -__expf(A_log[d * D_STATE + n]);

    float4 cwv = *(const float4*)(cw + d * 4);
    float cbd = cb[d];

    float st[D_STATE] = {};
    float sdt = 0.f;

    size_t idx = ((size_t)(b * SEQLEN + j * CL)) * D_INNER + d;
    size_t xxi = ((size_t)(b * SEQLEN + j * CL)) * (2 * D_INNER) + d;
    const float* xr = xdbl + (size_t)(b * SEQLEN + j * CL) * XPROJ_N + DT_RANK;

    float w0 = 0.f, w1 = 0.f, w2 = 0.f;
    if (j) {
        w0 = xz[xxi - 3 * (2 * D_INNER)];
        w1 = xz[xxi - 2 * (2 * D_INNER)];
        w2 = xz[xxi - 1 * (2 * D_INNER)];
    }

    for (int l = 0; l < CL; l++) {
        float w3 = xz[xxi];
        float uv = silu_f(fmaf(cwv.w, w3, fmaf(cwv.z, w2,
                     fmaf(cwv.y, w1, fmaf(cwv.x, w0, cbd)))));
        float dtv = dt[idx];
        float du  = dtv * uv;
        sdt += dtv;
        float4 B0 = *(const float4*)(xr + 0);
        float4 B1 = *(const float4*)(xr + 4);
        float4 B2 = *(const float4*)(xr + 8);
        float4 B3 = *(const float4*)(xr + 12);
        float Bv[16] = {B0.x,B0.y,B0.z,B0.w, B1.x,B1.y,B1.z,B1.w,
                        B2.x,B2.y,B2.z,B2.w, B3.x,B3.y,B3.z,B3.w};
        #pragma unroll
        for (int n = 0; n < D_STATE; n++)
            st[n] = fmaf(st[n], __expf(dtv * Av[n]), du * Bv[n]);
        w0 = w1; w1 = w2; w2 = w3;
        idx += D_INNER;
        xxi += 2 * D_INNER;
        xr  += XPROJ_N;
    }

    size_t base = (size_t)(b * CH + j) * D_STATE * D_INNER + d;
    #pragma unroll
    for (int n = 0; n < D_STATE; n++)
        s_arr[base + (size_t)n * D_INNER] = st[n];
    sdt_arr[(size_t)(b * CH + j) * D_INNER + d] = sdt;
}

// ---------------------------------------------------------------------------
// Pass 2: combine chunk summaries; s_arr <- entering state per chunk.
// ---------------------------------------------------------------------------
__global__ __launch_bounds__(256) void scan_pass2(
    const float* __restrict__ A_log, const float* __restrict__ sdt_arr,
    float* __restrict__ s_arr)
{
    int t = blockIdx.x * 256 + threadIdx.x;
    int d = t & (D_INNER - 1);
    int n = (t >> 11) & (D_STATE - 1);
    int b = t >> 15;

    float Av = -__expf(A_log[d * D_STATE + n]);
    float init = 0.f;
    for (int j = 0; j < CH; j++) {
        size_t off = ((size_t)(b * CH + j) * D_STATE + n) * D_INNER + d;
        float sv  = s_arr[off];
        float sdt = sdt_arr[(size_t)(b * CH + j) * D_INNER + d];
        s_arr[off] = init;
        init = fmaf(init, __expf(Av * sdt), sv);
    }
}

// ---------------------------------------------------------------------------
// Pass 3 with FUSED conv+silu; y emitted as split-bf16 pair.
// ---------------------------------------------------------------------------
__global__ __launch_bounds__(256) void scan_pass3(
    const float* __restrict__ dt, const float* __restrict__ xz,
    const float* __restrict__ xdbl, const float* __restrict__ cw,
    const float* __restrict__ cb, const float* __restrict__ A_log,
    const float* __restrict__ Dp, const float* __restrict__ s_arr,
    unsigned short* __restrict__ y_hi, unsigned short* __restrict__ y_lo)
{
    int d = blockIdx.x * 256 + threadIdx.x;
    int j = blockIdx.y;
    int b = blockIdx.z;

    float Av[D_STATE];
    #pragma unroll
    for (int n = 0; n < D_STATE; n++)
        Av[n] = -__expf(A_log[d * D_STATE + n]);
    float Dd = Dp[d];
    float4 cwv = *(const float4*)(cw + d * 4);
    float cbd = cb[d];

    float st[D_STATE];
    size_t sbase = (size_t)(b * CH + j) * D_STATE * D_INNER + d;
    #pragma unroll
    for (int n = 0; n < D_STATE; n++)
        st[n] = s_arr[sbase + (size_t)n * D_INNER];

    size_t idx = ((size_t)(b * SEQLEN + j * CL)) * D_INNER + d;
    size_t xxi = ((size_t)(b * SEQLEN + j * CL)) * (2 * D_INNER) + d;
    const float* xr = xdbl + (size_t)(b * SEQLEN + j * CL) * XPROJ_N + DT_RANK;

    float w0 = 0.f, w1 = 0.f, w2 = 0.f;
    if (j) {
        w0 = xz[xxi - 3 * (2 * D_INNER)];
        w1 = xz[xxi - 2 * (2 * D_INNER)];
        w2 = xz[xxi - 1 * (2 * D_INNER)];
    }

    for (int l = 0; l < CL; l++) {
        float w3 = xz[xxi];
        float uv = silu_f(fmaf(cwv.w, w3, fmaf(cwv.z, w2,
                     fmaf(cwv.y, w1, fmaf(cwv.x, w0, cbd)))));
        float dtv = dt[idx];
        float du  = dtv * uv;
        float4 B0 = *(const float4*)(xr + 0);
        float4 B1 = *(const float4*)(xr + 4);
        float4 B2 = *(const float4*)(xr + 8);
        float4 B3 = *(const float4*)(xr + 12);
        float4 C0 = *(const float4*)(xr + 16);
        float4 C1 = *(const float4*)(xr + 20);
        float4 C2 = *(const float4*)(xr + 24);
        float4 C3 = *(const float4*)(xr + 28);
        float Bv[16] = {B0.x,B0.y,B0.z,B0.w, B1.x,B1.y,B1.z,B1.w,
                        B2.x,B2.y,B2.z,B2.w, B3.x,B3.y,B3.z,B3.w};
        float Cv[16] = {C0.x,C0.y,C0.z,C0.w, C1.x,C1.y,C1.z,C1.w,
                        C2.x,C2.y,C2.z,C2.w, C3.x,C3.y,C3.z,C3.w};
        float yt = 0.f;
        #pragma unroll
        for (int n = 0; n < D_STATE; n++) {
            float s = fmaf(st[n], __expf(dtv * Av[n]), du * Bv[n]);
            st[n] = s;
            yt = fmaf(s, Cv[n], yt);
        }
        float zv = xz[xxi + D_INNER];
        float yv = (yt + Dd * uv) * silu_f(zv);
        unsigned short h16 = f2bf(yv);
        y_hi[idx] = h16;
        y_lo[idx] = f2bf(yv - bf2f(h16));

        w0 = w1; w1 = w2; w2 = w3;
        idx += D_INNER;
        xxi += 2 * D_INNER;
        xr  += XPROJ_N;
    }
}

// ---------------------------------------------------------------------------
extern "C" void kernel_launch(void* const* d_in, const int* in_sizes, int n_in,
                              void* d_out, int out_size, void* d_ws, size_t ws_size,
                              hipStream_t stream)
{
    const float* x     = (const float*)d_in[0];
    const float* emb_w = (const float*)d_in[1];
    const float* emb_b = (const float*)d_in[2];
    const float* inw   = (const float*)d_in[3];
    const float* cw    = (const float*)d_in[4];
    const float* cb    = (const float*)d_in[5];
    const float* xpw   = (const float*)d_in[6];
    const float* dtw   = (const float*)d_in[7];
    const float* dtb   = (const float*)d_in[8];
    const float* Alog  = (const float*)d_in[9];
    const float* Dpar  = (const float*)d_in[10];
    const float* outw  = (const float*)d_in[11];

    float* out = (float*)d_out;

    // workspace layout
    float* ws    = (float*)d_ws;
    float* xz    = ws;                   // 8,388,608 fl  (first 4.2M fl reused
                                         //  as out_proj split-K partials)
    float* xd    = xz + 8388608;         //   196,608 fl
    float* dt    = xd + 196608;          // 4,194,304 fl
    float* sdt   = dt + 4194304;         //   131,072 fl
    float* s_arr = sdt + 131072;         // 2,097,152 fl
    float* xpart = s_arr + 2097152;      // 3,145,728 fl
    unsigned short* h_hi = (unsigned short*)(xpart + (size_t)KSPL * 196608);
    unsigned short* h_lo = h_hi + 2097152;
    unsigned short* y_hi = h_lo + 2097152;
    unsigned short* y_lo = y_hi + 4194304;
    unsigned short* wih_all = y_lo + 4194304;        // 4 x 4,194,304 us
    unsigned short* woh_all = wih_all + 4 * 4194304; // 4 x 2,097,152 us
    // total ~160 MB

    // bulk weight -> bf16 conversion (all 4 layers, once per call)
    tobf16_kernel<<<(NUM_BLK * 1048576 + 255) / 256, 256, 0, stream>>>(
        inw, wih_all, NUM_BLK * 1048576);
    tobf16_kernel<<<(NUM_BLK * 524288 + 255) / 256, 256, 0, stream>>>(
        outw, woh_all, NUM_BLK * 524288);

    embed_kernel<<<(ML * D_MODEL) / 256, 256, 0, stream>>>(x, emb_w, emb_b, h_hi, h_lo);

    for (int i = 0; i < NUM_BLK; i++) {
        const float* cw_i   = cw   + (size_t)i * D_INNER * D_CONV;
        const float* cb_i   = cb   + (size_t)i * D_INNER;
        const float* xpw_i  = xpw  + (size_t)i * XPROJ_N * D_INNER;
        const float* dtw_i  = dtw  + (size_t)i * D_INNER * DT_RANK;
        const float* dtb_i  = dtb  + (size_t)i * D_INNER;
        const float* Alog_i = Alog + (size_t)i * D_INNER * D_STATE;
        const float* Dp_i   = Dpar + (size_t)i * D_INNER;
        unsigned short* wih = wih_all + (size_t)i * 4194304;
        unsigned short* woh = woh_all + (size_t)i * 2097152;

        // xz = h @ in_w^T  (M=2048, N=4096, K=1024), 512 threads / 8 waves
        mfma_gemm<128, 128, 2, 4, 0, 1><<<dim3(4096 / 128, 2048 / 128), 512, 0, stream>>>(
            h_hi, h_lo, wih, xz, nullptr, nullptr, ML, 2 * D_INNER, D_MODEL);

        // x_dbl = conv-fused u @ xp_w^T  (split-K + reduce)
        xproj_splitk<<<dim3(2, ML / 64, KSPL), 256, 0, stream>>>(
            xz, cw_i, cb_i, xpw_i, xpart);
        xproj_reduce<<<(ML * XPROJ_N / 4) / 256, 256, 0, stream>>>(xpart, xd);

        // dt = softplus(dt_lo @ dt_w^T + dt_b)
        gemm_nt<1><<<dim3(D_INNER / 64, ML / 64), 256, 0, stream>>>(
            xd, XPROJ_N, dtw_i, DT_RANK, dtb_i, dt, D_INNER,
            ML, D_INNER, DT_RANK);

        // chunked parallel scan (conv fused into pass1/pass3)
        scan_pass1<<<dim3(D_INNER / 256, CH, BATCH), 256, 0, stream>>>(
            dt, xz, xd, cw_i, cb_i, Alog_i, s_arr, sdt);
        scan_pass2<<<(BATCH * D_INNER * D_STATE) / 256, 256, 0, stream>>>(
            Alog_i, sdt, s_arr);
        scan_pass3<<<dim3(D_INNER / 256, CH, BATCH), 256, 0, stream>>>(
            dt, xz, xd, cw_i, cb_i, Alog_i, Dp_i, s_arr, y_hi, y_lo);

        // out_proj: split-K=2, partials into dead xz region, then fused
        // reduce + silu (+ split for next block's h)
        mfma_gemm<64, 128, 2, 4, 0, 2><<<dim3(1024 / 128, 2048 / 64, 2), 512, 0, stream>>>(
            y_hi, y_lo, woh, xz, nullptr, nullptr, ML, D_MODEL, D_INNER);
        if (i == NUM_BLK - 1) {
            oproj_reduce<1><<<(ML * D_MODEL / 4) / 256, 256, 0, stream>>>(
                xz, out, nullptr, nullptr);
        } else {
            oproj_reduce<0><<<(ML * D_MODEL / 4) / 256, 256, 0, stream>>>(
                xz, nullptr, h_hi, h_lo);
        }
    }
}

// Round 8
// 793.127 us; speedup vs baseline: 6.9407x; 1.0497x over previous
//
#include <hip/hip_runtime.h>
#include <math.h>

#define D_MODEL  1024
#define D_STATE  16
#define D_CONV   4
#define D_INNER  2048
#define DT_RANK  64
#define NUM_BLK  4
#define BATCH    2
#define SEQLEN   1024
#define ML       (BATCH*SEQLEN)   // 2048 rows (b*l flattened)
#define XPROJ_N  (DT_RANK + 2*D_STATE)  // 96
#define XPROJ_NP 128              // padded N for MFMA xproj
#define CH       32               // chunks per sequence
#define CL       32               // chunk length
#define XKSPL    16               // split-K for xproj MFMA

typedef __attribute__((ext_vector_type(8))) short short8;
typedef __attribute__((ext_vector_type(4))) float f32x4;

__device__ __forceinline__ float silu_f(float x) {
    return x / (1.0f + __expf(-x));
}
__device__ __forceinline__ float softplus_f(float x) {
    if (x > 15.0f) return x;
    return __logf(1.0f + __expf(x));
}
__device__ __forceinline__ unsigned short f2bf(float x) {
    unsigned int u = __float_as_uint(x);
    u += 0x7FFFu + ((u >> 16) & 1u);
    return (unsigned short)(u >> 16);
}
__device__ __forceinline__ float bf2f(unsigned short h) {
    return __uint_as_float(((unsigned int)h) << 16);
}

// ---------------------------------------------------------------------------
// Embedding -> split bf16 pair
// ---------------------------------------------------------------------------
__global__ __launch_bounds__(256) void embed_kernel(
    const float* __restrict__ x, const float* __restrict__ ew,
    const float* __restrict__ eb,
    unsigned short* __restrict__ h_hi, unsigned short* __restrict__ h_lo)
{
    int t  = blockIdx.x * 256 + threadIdx.x;
    int d  = t & (D_MODEL - 1);
    int bl = t >> 10;
    float v = fmaf(x[bl], ew[d], eb[d]);
    unsigned short h16 = f2bf(v);
    h_hi[t] = h16;
    h_lo[t] = f2bf(v - bf2f(h16));
}

// ---------------------------------------------------------------------------
// fp32 -> bf16 convert (bulk weights), vectorized x4
// ---------------------------------------------------------------------------
__global__ __launch_bounds__(256) void tobf16_kernel(
    const float* __restrict__ src, unsigned short* __restrict__ dst, int n4)
{
    int t = blockIdx.x * 256 + threadIdx.x;
    if (t >= n4) return;
    float4 v = ((const float4*)src)[t];
    ushort4 h;
    h.x = f2bf(v.x); h.y = f2bf(v.y); h.z = f2bf(v.z); h.w = f2bf(v.w);
    ((ushort4*)dst)[t] = h;
}

// ---------------------------------------------------------------------------
// xp_w (4,96,2048) fp32 -> (4,128,2048) bf16, rows 96..127 zero.
// ---------------------------------------------------------------------------
__global__ __launch_bounds__(256) void xpw_pad_kernel(
    const float* __restrict__ src, unsigned short* __restrict__ dst)
{
    int t  = blockIdx.x * 256 + threadIdx.x;  // over 4*128*512 k4-groups
    int k4 = t & 511;
    int n  = (t >> 9) & 127;
    int i  = t >> 16;
    ushort4 h = {0, 0, 0, 0};
    if (n < XPROJ_N) {
        float4 v = *(const float4*)(src + ((size_t)(i * XPROJ_N + n) * D_INNER + k4 * 4));
        h.x = f2bf(v.x); h.y = f2bf(v.y); h.z = f2bf(v.z); h.w = f2bf(v.w);
    }
    *(ushort4*)(dst + ((size_t)(i * XPROJ_NP + n) * D_INNER + k4 * 4)) = h;
}

// ---------------------------------------------------------------------------
// Causal conv(4) + silu -> u as exact bf16 hi/lo pair. x4 over d.
// ---------------------------------------------------------------------------
__global__ __launch_bounds__(256) void conv_split_kernel(
    const float* __restrict__ xz, const float* __restrict__ cw,
    const float* __restrict__ cb,
    unsigned short* __restrict__ u_hi, unsigned short* __restrict__ u_lo)
{
    int t  = blockIdx.x * 256 + threadIdx.x;  // over ML*D_INNER/4
    int d4 = t & (D_INNER / 4 - 1);
    int bl = t >> 9;
    int l  = bl & (SEQLEN - 1);
    int d  = d4 * 4;

    const float* base = xz + (size_t)bl * (2 * D_INNER) + d;
    float4 z4 = make_float4(0.f, 0.f, 0.f, 0.f);
    float4 x3 = *(const float4*)base;
    float4 x2 = (l >= 1) ? *(const float4*)(base - 1 * (2 * D_INNER)) : z4;
    float4 x1 = (l >= 2) ? *(const float4*)(base - 2 * (2 * D_INNER)) : z4;
    float4 x0 = (l >= 3) ? *(const float4*)(base - 3 * (2 * D_INNER)) : z4;
    float4 c0 = *(const float4*)(cw + (d + 0) * 4);
    float4 c1 = *(const float4*)(cw + (d + 1) * 4);
    float4 c2 = *(const float4*)(cw + (d + 2) * 4);
    float4 c3 = *(const float4*)(cw + (d + 3) * 4);
    float4 cbv = *(const float4*)(cb + d);

    float u0 = silu_f(cbv.x + c0.x*x0.x + c0.y*x1.x + c0.z*x2.x + c0.w*x3.x);
    float u1 = silu_f(cbv.y + c1.x*x0.y + c1.y*x1.y + c1.z*x2.y + c1.w*x3.y);
    float u2 = silu_f(cbv.z + c2.x*x0.z + c2.y*x1.z + c2.z*x2.z + c2.w*x3.z);
    float u3 = silu_f(cbv.w + c3.x*x0.w + c3.y*x1.w + c3.z*x2.w + c3.w*x3.w);

    ushort4 h, lo;
    h.x = f2bf(u0); lo.x = f2bf(u0 - bf2f(h.x));
    h.y = f2bf(u1); lo.y = f2bf(u1 - bf2f(h.y));
    h.z = f2bf(u2); lo.z = f2bf(u2 - bf2f(h.z));
    h.w = f2bf(u3); lo.w = f2bf(u3 - bf2f(h.w));
    ((ushort4*)u_hi)[t] = h;
    ((ushort4*)u_lo)[t] = lo;
}

// ---------------------------------------------------------------------------
// 2-term split-bf16 MFMA NT GEMM: C = act( (Ahi+Alo) @ Whi^T )
// LDS swizzle: 16B part p of row r stored at granule (p + ((r>>1)&3)) & 3.
// KSPLIT>1: blockIdx.z selects K-segment; raw fp32 partial to Cf + z*M*N.
// EPI: 0 fp32, 1 silu fp32, 2 silu->bf16 pair, 3 softplus(v+bias[n]) fp32
// ---------------------------------------------------------------------------
template<int BM, int BN, int WM, int WN, int EPI, int KSPLIT>
__global__ __launch_bounds__(WM*WN*64) void mfma_gemm(
    const unsigned short* __restrict__ Ahi, const unsigned short* __restrict__ Alo,
    const unsigned short* __restrict__ Whi,
    float* __restrict__ Cf, unsigned short* __restrict__ Chi,
    unsigned short* __restrict__ Clo, const float* __restrict__ bias,
    int M, int N, int K)
{
    constexpr int NW  = WM * WN;
    constexpr int WTM = BM / WM;
    constexpr int WTN = BN / WN;
    constexpr int MT  = WTM / 16;
    constexpr int NT  = WTN / 16;
    constexpr int NCH = (2*BM + BN) / 16;   // 1KB chunks per K-tile
    constexpr int CPW = NCH / NW;

    __shared__ unsigned short lds[(2*BM + BN) * 32];

    const int tid  = threadIdx.x;
    const int wave = tid >> 6;
    const int lane = tid & 63;
    const int m0 = blockIdx.y * BM;
    const int n0 = blockIdx.x * BN;
    const int wm0 = (wave % WM) * WTM;
    const int wn0 = (wave / WM) * WTN;
    const int lrow = lane & 15;
    const int kqi  = lane >> 4;             // k 16B-part index 0..3

    const int rc = lane >> 2;
    const int po = ((lane & 3) - (rc >> 1)) & 3;

    const unsigned short* gsrc[CPW];
    unsigned short* ldst[CPW];
    #pragma unroll
    for (int cc = 0; cc < CPW; cc++) {
        int c  = wave * CPW + cc;
        int r0 = c * 16;
        const unsigned short* s; int row;
        if      (r0 < BM)        { s = Ahi; row = m0 + r0; }
        else if (r0 < 2*BM)      { s = Alo; row = m0 + r0 - BM; }
        else                     { s = Whi; row = n0 + r0 - 2*BM; }
        gsrc[cc] = s + (size_t)(row + rc) * K + po * 8;
        ldst[cc] = &lds[c * 512];
    }

    f32x4 acc[MT][NT] = {};

    const int kseg = K / KSPLIT;
    const int kz   = (KSPLIT > 1) ? blockIdx.z : 0;
    const int kbeg = kz * kseg;
    const int kend = kbeg + kseg;

    for (int kt = kbeg; kt < kend; kt += 32) {
        __syncthreads();
        #pragma unroll
        for (int cc = 0; cc < CPW; cc++)
            __builtin_amdgcn_global_load_lds(
                (const __attribute__((address_space(1))) unsigned int*)(gsrc[cc] + kt),
                (__attribute__((address_space(3))) unsigned int*)ldst[cc],
                16, 0, 0);
        asm volatile("s_waitcnt vmcnt(0)" ::: "memory");
        __syncthreads();

        short8 ahi[MT], alo[MT], bhi[NT];
        #pragma unroll
        for (int i = 0; i < MT; i++) {
            int r = wm0 + i * 16 + lrow;
            int o = (kqi + ((r >> 1) & 3)) & 3;
            ahi[i] = *(const short8*)&lds[r * 32 + o * 8];
            alo[i] = *(const short8*)&lds[(BM + r) * 32 + o * 8];
        }
        #pragma unroll
        for (int j = 0; j < NT; j++) {
            int r = wn0 + j * 16 + lrow;
            int o = (kqi + ((r >> 1) & 3)) & 3;
            bhi[j] = *(const short8*)&lds[(2*BM + r) * 32 + o * 8];
        }
        #pragma unroll
        for (int i = 0; i < MT; i++)
            #pragma unroll
            for (int j = 0; j < NT; j++) {
                acc[i][j] = __builtin_amdgcn_mfma_f32_16x16x32_bf16(ahi[i], bhi[j], acc[i][j], 0, 0, 0);
                acc[i][j] = __builtin_amdgcn_mfma_f32_16x16x32_bf16(alo[i], bhi[j], acc[i][j], 0, 0, 0);
            }
    }

    const int orow = (lane >> 4) * 4;
    float* Cfz = Cf + (KSPLIT > 1 ? (size_t)kz * M * N : 0);
    #pragma unroll
    for (int i = 0; i < MT; i++) {
        #pragma unroll
        for (int j = 0; j < NT; j++) {
            #pragma unroll
            for (int r = 0; r < 4; r++) {
                int gm = m0 + wm0 + i * 16 + orow + r;
                int gn = n0 + wn0 + j * 16 + lrow;
                size_t off = (size_t)gm * N + gn;
                float v = acc[i][j][r];
                if (KSPLIT > 1 || EPI == 0) {
                    Cfz[off] = v;
                } else if (EPI == 1) {
                    Cf[off] = silu_f(v);
                } else if (EPI == 3) {
                    Cf[off] = softplus_f(v + bias[gn]);
                } else {
                    float s = silu_f(v);
                    unsigned short h16 = f2bf(s);
                    Chi[off] = h16;
                    Clo[off] = f2bf(s - bf2f(h16));
                }
            }
        }
    }
}

// ---------------------------------------------------------------------------
// out_proj split-K reduce: sum 2 partial planes, silu, emit.
// FINAL=1 -> fp32 to out; FINAL=0 -> split bf16 pair (next block's h).
// ---------------------------------------------------------------------------
template<int FINAL>
__global__ __launch_bounds__(256) void oproj_reduce(
    const float* __restrict__ P, float* __restrict__ outf,
    unsigned short* __restrict__ hi, unsigned short* __restrict__ lo)
{
    int t = blockIdx.x * 256 + threadIdx.x;   // 0 .. ML*D_MODEL/4-1
    float4 a = ((const float4*)P)[t];
    float4 b = ((const float4*)(P + (size_t)ML * D_MODEL))[t];
    float4 s;
    s.x = silu_f(a.x + b.x); s.y = silu_f(a.y + b.y);
    s.z = silu_f(a.z + b.z); s.w = silu_f(a.w + b.w);
    if (FINAL) {
        ((float4*)outf)[t] = s;
    } else {
        ushort4 h, l;
        h.x = f2bf(s.x); l.x = f2bf(s.x - bf2f(h.x));
        h.y = f2bf(s.y); l.y = f2bf(s.y - bf2f(h.y));
        h.z = f2bf(s.z); l.z = f2bf(s.z - bf2f(h.z));
        h.w = f2bf(s.w); l.w = f2bf(s.w - bf2f(h.w));
        ((ushort4*)hi)[t] = h;
        ((ushort4*)lo)[t] = l;
    }
}

// ---------------------------------------------------------------------------
// xproj split-K reduce: sum 16 planes of [ML][128]; write xd fp32 [ML][96],
// and dt_lo cols (0..63) additionally as bf16 hi/lo pair.
// ---------------------------------------------------------------------------
__global__ __launch_bounds__(256) void xproj_reduce2(
    const float* __restrict__ P, float* __restrict__ xd,
    unsigned short* __restrict__ dh, unsigned short* __restrict__ dl)
{
    int t = blockIdx.x * 256 + threadIdx.x;   // over ML*32 c4-groups
    int m = t >> 5;
    int c = (t & 31) * 4;
    if (c >= XPROJ_N) return;
    const float* p = P + (size_t)m * XPROJ_NP + c;
    float4 s = *(const float4*)p;
    #pragma unroll
    for (int z = 1; z < XKSPL; z++) {
        float4 v = *(const float4*)(p + (size_t)z * ML * XPROJ_NP);
        s.x += v.x; s.y += v.y; s.z += v.z; s.w += v.w;
    }
    *(float4*)(xd + (size_t)m * XPROJ_N + c) = s;
    if (c < DT_RANK) {
        ushort4 h, l;
        h.x = f2bf(s.x); l.x = f2bf(s.x - bf2f(h.x));
        h.y = f2bf(s.y); l.y = f2bf(s.y - bf2f(h.y));
        h.z = f2bf(s.z); l.z = f2bf(s.z - bf2f(h.z));
        h.w = f2bf(s.w); l.w = f2bf(s.w - bf2f(h.w));
        *(ushort4*)(dh + (size_t)m * DT_RANK + c) = h;
        *(ushort4*)(dl + (size_t)m * DT_RANK + c) = l;
    }
}

// ---------------------------------------------------------------------------
// Scan pass 1 (u from bf16 pair).
// ---------------------------------------------------------------------------
__global__ __launch_bounds__(256) void scan_pass1(
    const float* __restrict__ dt,
    const unsigned short* __restrict__ u_hi, const unsigned short* __restrict__ u_lo,
    const float* __restrict__ xdbl, const float* __restrict__ A_log,
    float* __restrict__ s_arr, float* __restrict__ sdt_arr)
{
    int d = blockIdx.x * 256 + threadIdx.x;
    int j = blockIdx.y;
    int b = blockIdx.z;

    float Av[D_STATE];
    #pragma unroll
    for (int n = 0; n < D_STATE; n++)
        Av[n] = -__expf(A_log[d * D_STATE + n]);

    float st[D_STATE] = {};
    float sdt = 0.f;

    size_t idx = ((size_t)(b * SEQLEN + j * CL)) * D_INNER + d;
    const float* xr = xdbl + (size_t)(b * SEQLEN + j * CL) * XPROJ_N + DT_RANK;

    for (int l = 0; l < CL; l++) {
        float uv  = bf2f(u_hi[idx]) + bf2f(u_lo[idx]);
        float dtv = dt[idx];
        float du  = dtv * uv;
        sdt += dtv;
        float4 B0 = *(const float4*)(xr + 0);
        float4 B1 = *(const float4*)(xr + 4);
        float4 B2 = *(const float4*)(xr + 8);
        float4 B3 = *(const float4*)(xr + 12);
        float Bv[16] = {B0.x,B0.y,B0.z,B0.w, B1.x,B1.y,B1.z,B1.w,
                        B2.x,B2.y,B2.z,B2.w, B3.x,B3.y,B3.z,B3.w};
        #pragma unroll
        for (int n = 0; n < D_STATE; n++)
            st[n] = fmaf(st[n], __expf(dtv * Av[n]), du * Bv[n]);
        idx += D_INNER;
        xr  += XPROJ_N;
    }

    size_t base = (size_t)(b * CH + j) * D_STATE * D_INNER + d;
    #pragma unroll
    for (int n = 0; n < D_STATE; n++)
        s_arr[base + (size_t)n * D_INNER] = st[n];
    sdt_arr[(size_t)(b * CH + j) * D_INNER + d] = sdt;
}

// ---------------------------------------------------------------------------
// Pass 2: combine chunk summaries; s_arr <- entering state per chunk.
// ---------------------------------------------------------------------------
__global__ __launch_bounds__(256) void scan_pass2(
    const float* __restrict__ A_log, const float* __restrict__ sdt_arr,
    float* __restrict__ s_arr)
{
    int t = blockIdx.x * 256 + threadIdx.x;
    int d = t & (D_INNER - 1);
    int n = (t >> 11) & (D_STATE - 1);
    int b = t >> 15;

    float Av = -__expf(A_log[d * D_STATE + n]);
    float init = 0.f;
    for (int j = 0; j < CH; j++) {
        size_t off = ((size_t)(b * CH + j) * D_STATE + n) * D_INNER + d;
        float sv  = s_arr[off];
        float sdt = sdt_arr[(size_t)(b * CH + j) * D_INNER + d];
        s_arr[off] = init;
        init = fmaf(init, __expf(Av * sdt), sv);
    }
}

// ---------------------------------------------------------------------------
// Pass 3 (u from bf16 pair); y emitted as split-bf16 pair.
// ---------------------------------------------------------------------------
__global__ __launch_bounds__(256) void scan_pass3(
    const float* __restrict__ dt,
    const unsigned short* __restrict__ u_hi, const unsigned short* __restrict__ u_lo,
    const float* __restrict__ xz, const float* __restrict__ xdbl,
    const float* __restrict__ A_log, const float* __restrict__ Dp,
    const float* __restrict__ s_arr,
    unsigned short* __restrict__ y_hi, unsigned short* __restrict__ y_lo)
{
    int d = blockIdx.x * 256 + threadIdx.x;
    int j = blockIdx.y;
    int b = blockIdx.z;

    float Av[D_STATE];
    #pragma unroll
    for (int n = 0; n < D_STATE; n++)
        Av[n] = -__expf(A_log[d * D_STATE + n]);
    float Dd = Dp[d];

    float st[D_STATE];
    size_t sbase = (size_t)(b * CH + j) * D_STATE * D_INNER + d;
    #pragma unroll
    for (int n = 0; n < D_STATE; n++)
        st[n] = s_arr[sbase + (size_t)n * D_INNER];

    size_t idx  = ((size_t)(b * SEQLEN + j * CL)) * D_INNER + d;
    size_t zidx = ((size_t)(b * SEQLEN + j * CL)) * (2 * D_INNER) + D_INNER + d;
    const float* xr = xdbl + (size_t)(b * SEQLEN + j * CL) * XPROJ_N + DT_RANK;

    for (int l = 0; l < CL; l++) {
        float uv  = bf2f(u_hi[idx]) + bf2f(u_lo[idx]);
        float dtv = dt[idx];
        float du  = dtv * uv;
        float4 B0 = *(const float4*)(xr + 0);
        float4 B1 = *(const float4*)(xr + 4);
        float4 B2 = *(const float4*)(xr + 8);
        float4 B3 = *(const float4*)(xr + 12);
        float4 C0 = *(const float4*)(xr + 16);
        float4 C1 = *(const float4*)(xr + 20);
        float4 C2 = *(const float4*)(xr + 24);
        float4 C3 = *(const float4*)(xr + 28);
        float Bv[16] = {B0.x,B0.y,B0.z,B0.w, B1.x,B1.y,B1.z,B1.w,
                        B2.x,B2.y,B2.z,B2.w, B3.x,B3.y,B3.z,B3.w};
        float Cv[16] = {C0.x,C0.y,C0.z,C0.w, C1.x,C1.y,C1.z,C1.w,
                        C2.x,C2.y,C2.z,C2.w, C3.x,C3.y,C3.z,C3.w};
        float yt = 0.f;
        #pragma unroll
        for (int n = 0; n < D_STATE; n++) {
            float s = fmaf(st[n], __expf(dtv * Av[n]), du * Bv[n]);
            st[n] = s;
            yt = fmaf(s, Cv[n], yt);
        }
        float zv = xz[zidx];
        float yv = (yt + Dd * uv) * silu_f(zv);
        unsigned short h16 = f2bf(yv);
        y_hi[idx] = h16;
        y_lo[idx] = f2bf(yv - bf2f(h16));

        idx  += D_INNER;
        zidx += 2 * D_INNER;
        xr   += XPROJ_N;
    }
}

// ---------------------------------------------------------------------------
extern "C" void kernel_launch(void* const* d_in, const int* in_sizes, int n_in,
                              void* d_out, int out_size, void* d_ws, size_t ws_size,
                              hipStream_t stream)
{
    const float* x     = (const float*)d_in[0];
    const float* emb_w = (const float*)d_in[1];
    const float* emb_b = (const float*)d_in[2];
    const float* inw   = (const float*)d_in[3];
    const float* cw    = (const float*)d_in[4];
    const float* cb    = (const float*)d_in[5];
    const float* xpw   = (const float*)d_in[6];
    const float* dtw   = (const float*)d_in[7];
    const float* dtb   = (const float*)d_in[8];
    const float* Alog  = (const float*)d_in[9];
    const float* Dpar  = (const float*)d_in[10];
    const float* outw  = (const float*)d_in[11];

    float* out = (float*)d_out;

    // workspace layout (~148 MB)
    float* ws    = (float*)d_ws;
    float* xz    = ws;                   // 8,388,608 fl (first half reused as
                                         //  out_proj split-K partials)
    float* xd    = xz + 8388608;         //   196,608 fl
    float* dtbuf = xd + 196608;          // 4,194,304 fl (xproj partials live
                                         //  here before dt is written)
    float* sdt   = dtbuf + 4194304;      //   131,072 fl
    float* s_arr = sdt + 131072;         // 2,097,152 fl
    // u pair regions double as h pair (h = first 2,097,152 of each)
    unsigned short* u_hi = (unsigned short*)(s_arr + 2097152);  // 4,194,304 us
    unsigned short* u_lo = u_hi + 4194304;                      // 4,194,304 us
    unsigned short* h_hi = u_hi;
    unsigned short* h_lo = u_lo;
    unsigned short* y_hi = u_lo + 4194304;
    unsigned short* y_lo = y_hi + 4194304;
    unsigned short* dtlo_hi = y_lo + 4194304;    // 131,072 us
    unsigned short* dtlo_lo = dtlo_hi + 131072;  // 131,072 us
    unsigned short* wih_all = dtlo_lo + 131072;        // 4 x 4,194,304
    unsigned short* woh_all = wih_all + 4 * 4194304;   // 4 x 2,097,152
    unsigned short* wxp_all = woh_all + 4 * 2097152;   // 4 x 262,144
    unsigned short* wdt_all = wxp_all + 4 * 262144;    // 4 x 131,072

    // bulk weight conversions (once per call)
    tobf16_kernel<<<(NUM_BLK * 1048576 + 255) / 256, 256, 0, stream>>>(
        inw, wih_all, NUM_BLK * 1048576);
    tobf16_kernel<<<(NUM_BLK * 524288 + 255) / 256, 256, 0, stream>>>(
        outw, woh_all, NUM_BLK * 524288);
    tobf16_kernel<<<(NUM_BLK * 32768 + 255) / 256, 256, 0, stream>>>(
        dtw, wdt_all, NUM_BLK * 32768);
    xpw_pad_kernel<<<(NUM_BLK * XPROJ_NP * 512) / 256, 256, 0, stream>>>(
        xpw, wxp_all);

    embed_kernel<<<(ML * D_MODEL) / 256, 256, 0, stream>>>(x, emb_w, emb_b, h_hi, h_lo);

    for (int i = 0; i < NUM_BLK; i++) {
        const float* cw_i   = cw   + (size_t)i * D_INNER * D_CONV;
        const float* cb_i   = cb   + (size_t)i * D_INNER;
        const float* dtb_i  = dtb  + (size_t)i * D_INNER;
        const float* Alog_i = Alog + (size_t)i * D_INNER * D_STATE;
        const float* Dp_i   = Dpar + (size_t)i * D_INNER;
        unsigned short* wih = wih_all + (size_t)i * 4194304;
        unsigned short* woh = woh_all + (size_t)i * 2097152;
        unsigned short* wxp = wxp_all + (size_t)i * 262144;
        unsigned short* wdt = wdt_all + (size_t)i * 131072;

        // 1) xz = h @ in_w^T  (M=2048, N=4096, K=1024)
        mfma_gemm<128, 128, 2, 4, 0, 1><<<dim3(32, 16), 512, 0, stream>>>(
            h_hi, h_lo, wih, xz, nullptr, nullptr, nullptr, ML, 2 * D_INNER, D_MODEL);

        // 2) u = silu(conv(x-half)) -> bf16 pair (overwrites h region)
        conv_split_kernel<<<(ML * D_INNER / 4) / 256, 256, 0, stream>>>(
            xz, cw_i, cb_i, u_hi, u_lo);

        // 3) x_dbl = u @ xp_w^T  MFMA, N padded to 128, split-K=16 ->
        //    partials in dtbuf region
        mfma_gemm<64, 128, 2, 4, 0, XKSPL><<<dim3(1, 32, XKSPL), 512, 0, stream>>>(
            u_hi, u_lo, wxp, dtbuf, nullptr, nullptr, nullptr, ML, XPROJ_NP, D_INNER);

        // 4) reduce -> xd fp32 (96 cols) + dt_lo bf16 pair (64 cols)
        xproj_reduce2<<<(ML * 32) / 256, 256, 0, stream>>>(
            dtbuf, xd, dtlo_hi, dtlo_lo);

        // 5) dt = softplus(dt_lo @ dt_w^T + dt_b)  MFMA (K=64) -> dtbuf
        mfma_gemm<64, 128, 2, 4, 3, 1><<<dim3(16, 32), 512, 0, stream>>>(
            dtlo_hi, dtlo_lo, wdt, dtbuf, nullptr, nullptr, dtb_i,
            ML, D_INNER, DT_RANK);

        // 6-8) chunked parallel scan
        scan_pass1<<<dim3(D_INNER / 256, CH, BATCH), 256, 0, stream>>>(
            dtbuf, u_hi, u_lo, xd, Alog_i, s_arr, sdt);
        scan_pass2<<<(BATCH * D_INNER * D_STATE) / 256, 256, 0, stream>>>(
            Alog_i, sdt, s_arr);
        scan_pass3<<<dim3(D_INNER / 256, CH, BATCH), 256, 0, stream>>>(
            dtbuf, u_hi, u_lo, xz, xd, Alog_i, Dp_i, s_arr, y_hi, y_lo);

        // 9) out_proj split-K=2, partials into dead xz region
        mfma_gemm<64, 128, 2, 4, 0, 2><<<dim3(8, 32, 2), 512, 0, stream>>>(
            y_hi, y_lo, woh, xz, nullptr, nullptr, nullptr, ML, D_MODEL, D_INNER);

        // 10) reduce + silu (+ split for next block's h)
        if (i == NUM_BLK - 1) {
            oproj_reduce<1><<<(ML * D_MODEL / 4) / 256, 256, 0, stream>>>(
                xz, out, nullptr, nullptr);
        } else {
            oproj_reduce<0><<<(ML * D_MODEL / 4) / 256, 256, 0, stream>>>(
                xz, nullptr, h_hi, h_lo);
        }
    }
}